// Round 1
// baseline (4439.624 us; speedup 1.0000x reference)
//
#include <hip/hip_runtime.h>
#include <math.h>

// Problem constants
static constexpr int Bb = 2;
static constexpr int Tt = 4096;
static constexpr int Cc = 512;
static constexpr int Hh = 8;
static constexpr int Dd = 64;          // head dim
static constexpr int Mtot = Bb * Tt;   // 8192 rows

// ---------------------------------------------------------------------------
// GEMM: y[m][n] = sum_k x[m][k] * w[n][k] + bias[n]   (torch Linear: x @ W^T + b)
// MODE 0: write to headed layout out[((b*H + n/D)*T + t)*D + n%D], m = b*T + t
// MODE 1: write flat out[m*C + n]
// Tile 64x64, BK=32, 256 threads, 4x4 per thread. k-major LDS (pad 68).
// ---------------------------------------------------------------------------
template <int MODE>
__global__ __launch_bounds__(256)
void proj_gemm(const float* __restrict__ x, const float* __restrict__ w,
               const float* __restrict__ bias, float* __restrict__ out) {
    __shared__ float xs[32][68];   // [k][m] k-major, pad to 68 floats
    __shared__ float ws[32][68];   // [k][n]

    const int tid = threadIdx.x;
    const int tx = tid & 15;       // n direction
    const int ty = tid >> 4;       // m direction
    const int m0 = blockIdx.x * 64;
    const int n0 = blockIdx.y * 64;

    float acc[4][4] = {};

    for (int k0 = 0; k0 < Cc; k0 += 32) {
        #pragma unroll
        for (int i = 0; i < 2; ++i) {
            const int idx = tid + i * 256;      // 0..511
            const int r  = idx >> 3;            // tile row 0..63
            const int c4 = idx & 7;             // float4 col 0..7  (32 cols)
            const float4 a4 = *reinterpret_cast<const float4*>(
                &x[(size_t)(m0 + r) * Cc + k0 + c4 * 4]);
            xs[c4 * 4 + 0][r] = a4.x;
            xs[c4 * 4 + 1][r] = a4.y;
            xs[c4 * 4 + 2][r] = a4.z;
            xs[c4 * 4 + 3][r] = a4.w;
            const float4 b4 = *reinterpret_cast<const float4*>(
                &w[(size_t)(n0 + r) * Cc + k0 + c4 * 4]);
            ws[c4 * 4 + 0][r] = b4.x;
            ws[c4 * 4 + 1][r] = b4.y;
            ws[c4 * 4 + 2][r] = b4.z;
            ws[c4 * 4 + 3][r] = b4.w;
        }
        __syncthreads();
        #pragma unroll
        for (int kk = 0; kk < 32; ++kk) {
            const float4 a4 = *reinterpret_cast<const float4*>(&xs[kk][ty * 4]);
            const float4 b4 = *reinterpret_cast<const float4*>(&ws[kk][tx * 4]);
            const float a[4] = {a4.x, a4.y, a4.z, a4.w};
            const float b[4] = {b4.x, b4.y, b4.z, b4.w};
            #pragma unroll
            for (int i = 0; i < 4; ++i)
                #pragma unroll
                for (int j = 0; j < 4; ++j)
                    acc[i][j] += a[i] * b[j];
        }
        __syncthreads();
    }

    const float4 bias4 = *reinterpret_cast<const float4*>(&bias[n0 + tx * 4]);
    const float bv[4] = {bias4.x, bias4.y, bias4.z, bias4.w};

    #pragma unroll
    for (int i = 0; i < 4; ++i) {
        const int m = m0 + ty * 4 + i;
        float4 o4;
        o4.x = acc[i][0] + bv[0];
        o4.y = acc[i][1] + bv[1];
        o4.z = acc[i][2] + bv[2];
        o4.w = acc[i][3] + bv[3];
        if (MODE == 0) {
            // n-tile spans exactly one head: h = n0/64, d = tx*4..+3
            const int b = m / Tt, t = m % Tt;
            const int h = n0 / Dd;
            float* dst = &out[(((size_t)b * Hh + h) * Tt + t) * Dd + tx * 4];
            *reinterpret_cast<float4*>(dst) = o4;
        } else {
            float* dst = &out[(size_t)m * Cc + n0 + tx * 4];
            *reinterpret_cast<float4*>(dst) = o4;
        }
    }
}

// ---------------------------------------------------------------------------
// Causal flash attention, fp32. One thread per q-row (q + O acc in registers),
// K/V staged in LDS tiles of 64 rows. grid = (T/256, B*H), block = 256.
// Output written directly in [B,T,C] layout for the final projection.
// ---------------------------------------------------------------------------
__global__ __launch_bounds__(256)
void attn_kernel(const float* __restrict__ q, const float* __restrict__ k,
                 const float* __restrict__ v, float* __restrict__ out) {
    __shared__ float ks[64][64];
    __shared__ float vs[64][64];

    const int qt  = blockIdx.x;            // q tile of 256 rows
    const int bh  = blockIdx.y;            // b*H + h
    const int tid = threadIdx.x;
    const int qg  = qt * 256 + tid;        // this thread's global q row

    // load q row into registers
    const float* qbase = q + ((size_t)bh * Tt + qg) * Dd;
    float qreg[64];
    #pragma unroll
    for (int i = 0; i < 16; ++i) {
        const float4 t4 = *reinterpret_cast<const float4*>(qbase + i * 4);
        qreg[i * 4 + 0] = t4.x;
        qreg[i * 4 + 1] = t4.y;
        qreg[i * 4 + 2] = t4.z;
        qreg[i * 4 + 3] = t4.w;
    }

    float oacc[64] = {};
    float mval = -INFINITY;
    float lval = 0.f;

    const int ntiles = (qt + 1) * 4;       // K tiles of 64 covering k <= max q in block
    for (int kt = 0; kt < ntiles; ++kt) {
        __syncthreads();                    // previous tile's reads done
        const size_t base = ((size_t)bh * Tt + kt * 64) * Dd;
        #pragma unroll
        for (int i = 0; i < 4; ++i) {
            const int idx = tid + i * 256;  // 0..1023
            const int r  = idx >> 4;        // row 0..63
            const int c4 = idx & 15;        // float4 col 0..15
            const float4 kf = *reinterpret_cast<const float4*>(&k[base + r * 64 + c4 * 4]);
            *reinterpret_cast<float4*>(&ks[r][c4 * 4]) = kf;
            const float4 vf = *reinterpret_cast<const float4*>(&v[base + r * 64 + c4 * 4]);
            *reinterpret_cast<float4*>(&vs[r][c4 * 4]) = vf;
        }
        __syncthreads();

        const int jmax = min(64, qg - kt * 64 + 1);   // causal: k_global <= qg
        for (int j = 0; j < jmax; ++j) {
            float s = 0.f;
            #pragma unroll
            for (int d4 = 0; d4 < 16; ++d4) {
                const float4 kv = *reinterpret_cast<const float4*>(&ks[j][d4 * 4]);
                s += qreg[d4 * 4 + 0] * kv.x + qreg[d4 * 4 + 1] * kv.y +
                     qreg[d4 * 4 + 2] * kv.z + qreg[d4 * 4 + 3] * kv.w;
            }
            s *= 0.125f;                               // 1/sqrt(64)
            const float mnew = fmaxf(mval, s);
            const float corr = __expf(mval - mnew);    // 0 when mval = -inf
            const float p    = __expf(s - mnew);
            lval = lval * corr + p;
            mval = mnew;
            #pragma unroll
            for (int d4 = 0; d4 < 16; ++d4) {
                const float4 vv = *reinterpret_cast<const float4*>(&vs[j][d4 * 4]);
                oacc[d4 * 4 + 0] = oacc[d4 * 4 + 0] * corr + p * vv.x;
                oacc[d4 * 4 + 1] = oacc[d4 * 4 + 1] * corr + p * vv.y;
                oacc[d4 * 4 + 2] = oacc[d4 * 4 + 2] * corr + p * vv.z;
                oacc[d4 * 4 + 3] = oacc[d4 * 4 + 3] * corr + p * vv.w;
            }
        }
    }

    const float inv = 1.f / lval;
    const int b = bh / Hh, h = bh % Hh;
    float* obase = out + ((size_t)b * Tt + qg) * Cc + h * Dd;
    #pragma unroll
    for (int i = 0; i < 16; ++i) {
        float4 o4;
        o4.x = oacc[i * 4 + 0] * inv;
        o4.y = oacc[i * 4 + 1] * inv;
        o4.z = oacc[i * 4 + 2] * inv;
        o4.w = oacc[i * 4 + 3] * inv;
        *reinterpret_cast<float4*>(obase + i * 4) = o4;
    }
}

// ---------------------------------------------------------------------------
extern "C" void kernel_launch(void* const* d_in, const int* in_sizes, int n_in,
                              void* d_out, int out_size, void* d_ws, size_t ws_size,
                              hipStream_t stream) {
    const float* x  = (const float*)d_in[0];
    const float* wq = (const float*)d_in[1];
    const float* bq = (const float*)d_in[2];
    const float* wk = (const float*)d_in[3];
    const float* bk = (const float*)d_in[4];
    const float* wv = (const float*)d_in[5];
    const float* bv = (const float*)d_in[6];
    const float* wo = (const float*)d_in[7];
    const float* bo = (const float*)d_in[8];
    float* out = (float*)d_out;

    const size_t nElem = (size_t)Bb * Hh * Tt * Dd;   // 4M floats per buffer
    float* q    = (float*)d_ws;
    float* kbuf = q + nElem;
    float* vbuf = kbuf + nElem;
    float* oatt = vbuf + nElem;                        // [B,T,C] layout

    const dim3 gridP(Mtot / 64, Cc / 64);              // 128 x 8
    proj_gemm<0><<<gridP, 256, 0, stream>>>(x, wq, bq, q);
    proj_gemm<0><<<gridP, 256, 0, stream>>>(x, wk, bk, kbuf);
    proj_gemm<0><<<gridP, 256, 0, stream>>>(x, wv, bv, vbuf);

    attn_kernel<<<dim3(Tt / 256, Bb * Hh), 256, 0, stream>>>(q, kbuf, vbuf, oatt);

    proj_gemm<1><<<gridP, 256, 0, stream>>>(oatt, wo, bo, out);
}

// Round 3
// 1143.188 us; speedup vs baseline: 3.8835x; 3.8835x over previous
//
#include <hip/hip_runtime.h>
#include <math.h>

// Problem constants
static constexpr int Bb = 2;
static constexpr int Tt = 4096;
static constexpr int Cc = 512;
static constexpr int Hh = 8;
static constexpr int Dd = 64;          // head dim
static constexpr int Mtot = Bb * Tt;   // 8192 rows

// ---------------------------------------------------------------------------
// GEMM: y[m][n] = sum_k x[m][k] * w[n][k] + bias[n]   (torch Linear: x @ W^T + b)
// MODE 0: write to headed layout out[((b*H + n/D)*T + t)*D + n%D], m = b*T + t
// MODE 1: write flat out[m*C + n]
// Tile 64x64, BK=32, 256 threads, 4x4 per thread. k-major LDS (pad 68).
// ---------------------------------------------------------------------------
template <int MODE>
__global__ __launch_bounds__(256)
void proj_gemm(const float* __restrict__ x, const float* __restrict__ w,
               const float* __restrict__ bias, float* __restrict__ out) {
    __shared__ float xs[32][68];   // [k][m] k-major, pad to 68 floats
    __shared__ float ws[32][68];   // [k][n]

    const int tid = threadIdx.x;
    const int tx = tid & 15;       // n direction
    const int ty = tid >> 4;       // m direction
    const int m0 = blockIdx.x * 64;
    const int n0 = blockIdx.y * 64;

    float acc[4][4] = {};

    for (int k0 = 0; k0 < Cc; k0 += 32) {
        #pragma unroll
        for (int i = 0; i < 2; ++i) {
            const int idx = tid + i * 256;      // 0..511
            const int r  = idx >> 3;            // tile row 0..63
            const int c4 = idx & 7;             // float4 col 0..7  (32 cols)
            const float4 a4 = *reinterpret_cast<const float4*>(
                &x[(size_t)(m0 + r) * Cc + k0 + c4 * 4]);
            xs[c4 * 4 + 0][r] = a4.x;
            xs[c4 * 4 + 1][r] = a4.y;
            xs[c4 * 4 + 2][r] = a4.z;
            xs[c4 * 4 + 3][r] = a4.w;
            const float4 b4 = *reinterpret_cast<const float4*>(
                &w[(size_t)(n0 + r) * Cc + k0 + c4 * 4]);
            ws[c4 * 4 + 0][r] = b4.x;
            ws[c4 * 4 + 1][r] = b4.y;
            ws[c4 * 4 + 2][r] = b4.z;
            ws[c4 * 4 + 3][r] = b4.w;
        }
        __syncthreads();
        #pragma unroll
        for (int kk = 0; kk < 32; ++kk) {
            const float4 a4 = *reinterpret_cast<const float4*>(&xs[kk][ty * 4]);
            const float4 b4 = *reinterpret_cast<const float4*>(&ws[kk][tx * 4]);
            const float a[4] = {a4.x, a4.y, a4.z, a4.w};
            const float b[4] = {b4.x, b4.y, b4.z, b4.w};
            #pragma unroll
            for (int i = 0; i < 4; ++i)
                #pragma unroll
                for (int j = 0; j < 4; ++j)
                    acc[i][j] += a[i] * b[j];
        }
        __syncthreads();
    }

    const float4 bias4 = *reinterpret_cast<const float4*>(&bias[n0 + tx * 4]);
    const float bv[4] = {bias4.x, bias4.y, bias4.z, bias4.w};

    #pragma unroll
    for (int i = 0; i < 4; ++i) {
        const int m = m0 + ty * 4 + i;
        float4 o4;
        o4.x = acc[i][0] + bv[0];
        o4.y = acc[i][1] + bv[1];
        o4.z = acc[i][2] + bv[2];
        o4.w = acc[i][3] + bv[3];
        if (MODE == 0) {
            const int b = m / Tt, t = m % Tt;
            const int h = n0 / Dd;
            float* dst = &out[(((size_t)b * Hh + h) * Tt + t) * Dd + tx * 4];
            *reinterpret_cast<float4*>(dst) = o4;
        } else {
            float* dst = &out[(size_t)m * Cc + n0 + tx * 4];
            *reinterpret_cast<float4*>(dst) = o4;
        }
    }
}

// ---------------------------------------------------------------------------
// Causal flash attention, fp32, block-tiled.
// Block: 256 threads (16x16), BQ=64 q rows, BK=64 k rows per tile.
// S = Q K^T via 4x4 microtile GEMM (Q,K staged k-major in LDS),
// row softmax via 16-lane shfl_xor reduce (tx = lane bits 0..3),
// P written transposed into the K buffer (reuse), O += P V via 4x4 microtile.
// grid = (T/64, B*H). LDS = 16K (Qs) + 17K (Ks/Ps) + 16K (Vs) = 49K -> 3 blk/CU.
// ---------------------------------------------------------------------------
__global__ __launch_bounds__(256)
void attn_kernel(const float* __restrict__ q, const float* __restrict__ k,
                 const float* __restrict__ v, float* __restrict__ out) {
    __shared__ float qs[64][64];    // [d][m]  (k-major; unpadded: reads broadcast)
    __shared__ float kps[64][68];   // Ks: [d][n]  then reused as Ps: [n][m]
    __shared__ float vs[64][64];    // [n][d]  natural

    const int qt  = blockIdx.x;
    const int bh  = blockIdx.y;
    const int tid = threadIdx.x;
    const int tx  = tid & 15;       // S: n dir / O: d dir
    const int ty  = tid >> 4;       // m dir (q rows)

    // ---- stage Q tile transposed: qs[d][m] ----
    const size_t qbase = ((size_t)bh * Tt + qt * 64) * Dd;
    #pragma unroll
    for (int i = 0; i < 4; ++i) {
        const int idx = tid + i * 256;   // 0..1023
        const int r   = idx >> 4;        // q row 0..63
        const int c4  = idx & 15;        // float4 col
        const float4 t4 = *reinterpret_cast<const float4*>(&q[qbase + r * 64 + c4 * 4]);
        qs[c4 * 4 + 0][r] = t4.x;
        qs[c4 * 4 + 1][r] = t4.y;
        qs[c4 * 4 + 2][r] = t4.z;
        qs[c4 * 4 + 3][r] = t4.w;
    }

    float oacc[4][4] = {};
    float mrow[4] = {-INFINITY, -INFINITY, -INFINITY, -INFINITY};
    float lrow[4] = {};

    for (int kt = 0; kt <= qt; ++kt) {
        __syncthreads();   // prev PV reads done before overwriting Ks/Vs
        const size_t base = ((size_t)bh * Tt + kt * 64) * Dd;
        #pragma unroll
        for (int i = 0; i < 4; ++i) {
            const int idx = tid + i * 256;
            const int r   = idx >> 4;
            const int c4  = idx & 15;
            const float4 kf = *reinterpret_cast<const float4*>(&k[base + r * 64 + c4 * 4]);
            kps[c4 * 4 + 0][r] = kf.x;     // transposed: [d][n]
            kps[c4 * 4 + 1][r] = kf.y;
            kps[c4 * 4 + 2][r] = kf.z;
            kps[c4 * 4 + 3][r] = kf.w;
            const float4 vf = *reinterpret_cast<const float4*>(&v[base + r * 64 + c4 * 4]);
            *reinterpret_cast<float4*>(&vs[r][c4 * 4]) = vf;
        }
        __syncthreads();

        // ---- S = Q K^T (4x4 microtile) ----
        float sacc[4][4] = {};
        #pragma unroll 8
        for (int kk = 0; kk < 64; ++kk) {
            const float4 a4 = *reinterpret_cast<const float4*>(&qs[kk][ty * 4]);
            const float4 b4 = *reinterpret_cast<const float4*>(&kps[kk][tx * 4]);
            const float a[4] = {a4.x, a4.y, a4.z, a4.w};
            const float b[4] = {b4.x, b4.y, b4.z, b4.w};
            #pragma unroll
            for (int i = 0; i < 4; ++i)
                #pragma unroll
                for (int j = 0; j < 4; ++j)
                    sacc[i][j] += a[i] * b[j];
        }

        // ---- scale + causal mask (diagonal tile only) ----
        #pragma unroll
        for (int i = 0; i < 4; ++i)
            #pragma unroll
            for (int j = 0; j < 4; ++j)
                sacc[i][j] *= 0.125f;
        if (kt == qt) {
            #pragma unroll
            for (int i = 0; i < 4; ++i)
                #pragma unroll
                for (int j = 0; j < 4; ++j)
                    if (tx * 4 + j > ty * 4 + i) sacc[i][j] = -INFINITY;
        }

        // ---- online softmax (row stats across 16 tx lanes) ----
        float corr[4];
        #pragma unroll
        for (int i = 0; i < 4; ++i) {
            float tm = fmaxf(fmaxf(sacc[i][0], sacc[i][1]),
                             fmaxf(sacc[i][2], sacc[i][3]));
            tm = fmaxf(tm, __shfl_xor(tm, 1));
            tm = fmaxf(tm, __shfl_xor(tm, 2));
            tm = fmaxf(tm, __shfl_xor(tm, 4));
            tm = fmaxf(tm, __shfl_xor(tm, 8));
            const float mnew = fmaxf(mrow[i], tm);
            corr[i] = __expf(mrow[i] - mnew);   // 0 on first tile
            float rs = 0.f;
            #pragma unroll
            for (int j = 0; j < 4; ++j) {
                const float p = __expf(sacc[i][j] - mnew);
                sacc[i][j] = p;
                rs += p;
            }
            rs += __shfl_xor(rs, 1);
            rs += __shfl_xor(rs, 2);
            rs += __shfl_xor(rs, 4);
            rs += __shfl_xor(rs, 8);
            lrow[i] = lrow[i] * corr[i] + rs;
            mrow[i] = mnew;
            #pragma unroll
            for (int j = 0; j < 4; ++j)
                oacc[i][j] *= corr[i];
        }

        __syncthreads();   // all waves done reading Ks before P overwrites it

        // ---- write P transposed into kps: Ps[n][m] = P[m][n] ----
        #pragma unroll
        for (int i = 0; i < 4; ++i)
            #pragma unroll
            for (int j = 0; j < 4; ++j)
                kps[tx * 4 + j][ty * 4 + i] = sacc[i][j];

        __syncthreads();

        // ---- O += P V (4x4 microtile) ----
        #pragma unroll 8
        for (int kk = 0; kk < 64; ++kk) {
            const float4 a4 = *reinterpret_cast<const float4*>(&kps[kk][ty * 4]);
            const float4 b4 = *reinterpret_cast<const float4*>(&vs[kk][tx * 4]);
            const float a[4] = {a4.x, a4.y, a4.z, a4.w};
            const float b[4] = {b4.x, b4.y, b4.z, b4.w};
            #pragma unroll
            for (int i = 0; i < 4; ++i)
                #pragma unroll
                for (int j = 0; j < 4; ++j)
                    oacc[i][j] += a[i] * b[j];
        }
    }

    // ---- epilogue: normalize, write [B,T,C] ----
    const int b = bh / Hh, h = bh % Hh;
    #pragma unroll
    for (int i = 0; i < 4; ++i) {
        const int m  = ty * 4 + i;
        const int qg = qt * 64 + m;
        const float inv = 1.f / lrow[i];
        float4 o4;
        o4.x = oacc[i][0] * inv;
        o4.y = oacc[i][1] * inv;
        o4.z = oacc[i][2] * inv;
        o4.w = oacc[i][3] * inv;
        float* dst = out + ((size_t)b * Tt + qg) * Cc + h * Dd + tx * 4;
        *reinterpret_cast<float4*>(dst) = o4;
    }
}

// ---------------------------------------------------------------------------
extern "C" void kernel_launch(void* const* d_in, const int* in_sizes, int n_in,
                              void* d_out, int out_size, void* d_ws, size_t ws_size,
                              hipStream_t stream) {
    const float* x  = (const float*)d_in[0];
    const float* wq = (const float*)d_in[1];
    const float* bq = (const float*)d_in[2];
    const float* wk = (const float*)d_in[3];
    const float* bk = (const float*)d_in[4];
    const float* wv = (const float*)d_in[5];
    const float* bv = (const float*)d_in[6];
    const float* wo = (const float*)d_in[7];
    const float* bo = (const float*)d_in[8];
    float* out = (float*)d_out;

    const size_t nElem = (size_t)Bb * Hh * Tt * Dd;   // 4M floats per buffer
    float* q    = (float*)d_ws;
    float* kbuf = q + nElem;
    float* vbuf = kbuf + nElem;
    float* oatt = vbuf + nElem;                        // [B,T,C] layout

    const dim3 gridP(Mtot / 64, Cc / 64);              // 128 x 8
    proj_gemm<0><<<gridP, 256, 0, stream>>>(x, wq, bq, q);
    proj_gemm<0><<<gridP, 256, 0, stream>>>(x, wk, bk, kbuf);
    proj_gemm<0><<<gridP, 256, 0, stream>>>(x, wv, bv, vbuf);

    attn_kernel<<<dim3(Tt / 64, Bb * Hh), 256, 0, stream>>>(q, kbuf, vbuf, oatt);

    proj_gemm<1><<<gridP, 256, 0, stream>>>(oatt, wo, bo, out);
}

// Round 4
// 283.805 us; speedup vs baseline: 15.6432x; 4.0281x over previous
//
#include <hip/hip_runtime.h>
#include <math.h>

static constexpr int Bb = 2;
static constexpr int Tt = 4096;
static constexpr int Cc = 512;
static constexpr int Hh = 8;
static constexpr int Dd = 64;
static constexpr int Mtot = Bb * Tt;   // 8192

typedef __attribute__((ext_vector_type(8))) short short8;
typedef __attribute__((ext_vector_type(4))) float f32x4;

// fp32 -> bf16 round-to-nearest-even (finite inputs), header-version-proof
__device__ inline unsigned short f2bf(float f) {
    unsigned int u = __float_as_uint(f);
    u += 0x7fffu + ((u >> 16) & 1u);
    return (unsigned short)(u >> 16);
}

// ---------------------------------------------------------------------------
// cast fp32 -> bf16, 8 elems/thread, exact-size grid
// ---------------------------------------------------------------------------
__global__ __launch_bounds__(256)
void cast_f32_bf16(const float* __restrict__ src, unsigned short* __restrict__ dst) {
    const size_t i = ((size_t)blockIdx.x * 256 + threadIdx.x) * 8;
    const float4 a = *reinterpret_cast<const float4*>(src + i);
    const float4 b = *reinterpret_cast<const float4*>(src + i + 4);
    short8 o;
    o[0] = (short)f2bf(a.x); o[1] = (short)f2bf(a.y);
    o[2] = (short)f2bf(a.z); o[3] = (short)f2bf(a.w);
    o[4] = (short)f2bf(b.x); o[5] = (short)f2bf(b.y);
    o[6] = (short)f2bf(b.z); o[7] = (short)f2bf(b.w);
    *reinterpret_cast<short8*>(dst + i) = o;
}

// 4 weight matrices (each 512x512), blockIdx.y selects
__global__ __launch_bounds__(256)
void cast_w4(const float* __restrict__ w0, const float* __restrict__ w1,
             const float* __restrict__ w2, const float* __restrict__ w3,
             unsigned short* __restrict__ dst) {
    const float* srcs[4] = {w0, w1, w2, w3};
    const float* s = srcs[blockIdx.y];
    unsigned short* d = dst + (size_t)blockIdx.y * (Cc * Cc);
    const size_t i = ((size_t)blockIdx.x * 256 + threadIdx.x) * 8;
    const float4 a = *reinterpret_cast<const float4*>(s + i);
    const float4 b = *reinterpret_cast<const float4*>(s + i + 4);
    short8 o;
    o[0] = (short)f2bf(a.x); o[1] = (short)f2bf(a.y);
    o[2] = (short)f2bf(a.z); o[3] = (short)f2bf(a.w);
    o[4] = (short)f2bf(b.x); o[5] = (short)f2bf(b.y);
    o[6] = (short)f2bf(b.z); o[7] = (short)f2bf(b.w);
    *reinterpret_cast<short8*>(d + i) = o;
}

// ---------------------------------------------------------------------------
// V transpose: [B*H][T][D] bf16 -> [B*H][D][T] bf16, 64x64 tiles via LDS
// ---------------------------------------------------------------------------
__global__ __launch_bounds__(256)
void transpose_v(const unsigned short* __restrict__ vb, unsigned short* __restrict__ vtb) {
    __shared__ unsigned short tile[64][72];
    const int t0 = blockIdx.x * 64;
    const int bh = blockIdx.y;
    const int tid = threadIdx.x;
    #pragma unroll
    for (int i = 0; i < 2; ++i) {
        const int idx = tid + i * 256;
        const int r = idx >> 3, c8 = idx & 7;
        const short8 v8 = *reinterpret_cast<const short8*>(
            &vb[((size_t)bh * Tt + t0 + r) * Dd + c8 * 8]);
        #pragma unroll
        for (int e = 0; e < 8; ++e) tile[c8 * 8 + e][r] = (unsigned short)v8[e];
    }
    __syncthreads();
    #pragma unroll
    for (int i = 0; i < 2; ++i) {
        const int idx = tid + i * 256;
        const int dr = idx >> 3, tg = idx & 7;
        const short8 o = *reinterpret_cast<const short8*>(&tile[dr][tg * 8]);
        *reinterpret_cast<short8*>(&vtb[((size_t)bh * Dd + dr) * Tt + t0 + tg * 8]) = o;
    }
}

// ---------------------------------------------------------------------------
// bf16 MFMA GEMM: y[m][n] = sum_k A[m][k]*W[n][k] + bias[n]
// Tile 128x128, BK=32, 4 waves (2x2), each wave 64x64 = 4x4 frags of 16x16x32.
// MODE 0: bf16 out, headed layout [(b*H+h)*T + t]*D + d
// MODE 1: f32 out, flat [m*C + n]
// ---------------------------------------------------------------------------
template <int MODE>
__global__ __launch_bounds__(256)
void proj_mfma(const unsigned short* __restrict__ A, const unsigned short* __restrict__ Wb,
               const float* __restrict__ bias, void* __restrict__ outp) {
    __shared__ unsigned short As[128][32];
    __shared__ unsigned short Bs[128][32];

    const int tid = threadIdx.x;
    const int lane = tid & 63;
    const int w = tid >> 6;
    const int wr = w >> 1, wc = w & 1;
    const int l15 = lane & 15, lg = lane >> 4;
    const int m0 = blockIdx.x * 128, n0 = blockIdx.y * 128;

    f32x4 acc[4][4] = {};

    for (int k0 = 0; k0 < Cc; k0 += 32) {
        #pragma unroll
        for (int i = 0; i < 2; ++i) {
            const int idx = tid + i * 256;
            const int row = idx >> 2, g = idx & 3;
            *reinterpret_cast<short8*>(&As[row][g * 8]) =
                *reinterpret_cast<const short8*>(&A[(size_t)(m0 + row) * Cc + k0 + g * 8]);
            *reinterpret_cast<short8*>(&Bs[row][g * 8]) =
                *reinterpret_cast<const short8*>(&Wb[(size_t)(n0 + row) * Cc + k0 + g * 8]);
        }
        __syncthreads();
        short8 a[4], b[4];
        #pragma unroll
        for (int mi = 0; mi < 4; ++mi)
            a[mi] = *reinterpret_cast<const short8*>(&As[wr * 64 + mi * 16 + l15][lg * 8]);
        #pragma unroll
        for (int nj = 0; nj < 4; ++nj)
            b[nj] = *reinterpret_cast<const short8*>(&Bs[wc * 64 + nj * 16 + l15][lg * 8]);
        #pragma unroll
        for (int mi = 0; mi < 4; ++mi)
            #pragma unroll
            for (int nj = 0; nj < 4; ++nj)
                acc[mi][nj] = __builtin_amdgcn_mfma_f32_16x16x32_bf16(a[mi], b[nj], acc[mi][nj], 0, 0, 0);
        __syncthreads();
    }

    #pragma unroll
    for (int mi = 0; mi < 4; ++mi) {
        #pragma unroll
        for (int nj = 0; nj < 4; ++nj) {
            const int col = n0 + wc * 64 + nj * 16 + l15;
            const float bv = bias[col];
            #pragma unroll
            for (int r = 0; r < 4; ++r) {
                const int row = m0 + wr * 64 + mi * 16 + lg * 4 + r;
                const float val = acc[mi][nj][r] + bv;
                if (MODE == 0) {
                    const int b_ = row >> 12, t = row & (Tt - 1);
                    const int h = col >> 6, d = col & 63;
                    ((unsigned short*)outp)[(((size_t)b_ * Hh + h) * Tt + t) * Dd + d] = f2bf(val);
                } else {
                    ((float*)outp)[(size_t)row * Cc + col] = val;
                }
            }
        }
    }
}

// ---------------------------------------------------------------------------
// Causal flash attention, bf16 MFMA. Block = 4 waves, BQ=64 (16 q-rows/wave),
// KV tile = 64. K/Vt staged in LDS with 16B-granule XOR swizzle (T2).
// P redistributed C-frag -> A-frag via per-wave LDS slab (also f32->bf16).
// grid = (T/64 descending-work, B*H).
// ---------------------------------------------------------------------------
__global__ __launch_bounds__(256)
void attn_mfma(const unsigned short* __restrict__ qb, const unsigned short* __restrict__ kb,
               const unsigned short* __restrict__ vtb, unsigned short* __restrict__ ob) {
    __shared__ unsigned short Ks[64][64];    // [kv][d], granule-swizzled
    __shared__ unsigned short Vts[64][64];   // [d][kv], granule-swizzled
    __shared__ unsigned short Ps[64][72];    // [q_local][kv], per-wave 16-row slabs

    const int qt = ((int)gridDim.x - 1) - (int)blockIdx.x;  // long blocks first
    const int bh = blockIdx.y;
    const int tid = threadIdx.x;
    const int w = tid >> 6;
    const int lane = tid & 63;
    const int l15 = lane & 15, lg = lane >> 4;

    // Q fragments straight to registers (A-frag layout)
    short8 qf[2];
    {
        const unsigned short* qp =
            qb + ((size_t)bh * Tt + qt * 64 + w * 16 + l15) * Dd + lg * 8;
        qf[0] = *reinterpret_cast<const short8*>(qp);
        qf[1] = *reinterpret_cast<const short8*>(qp + 32);
    }

    f32x4 oacc[4] = {};
    float mrow[4], lrow[4];
    #pragma unroll
    for (int r = 0; r < 4; ++r) { mrow[r] = -INFINITY; lrow[r] = 0.f; }

    for (int kt = 0; kt <= qt; ++kt) {
        __syncthreads();   // prev tile's Vts reads complete
        #pragma unroll
        for (int i = 0; i < 2; ++i) {
            const int idx = tid + i * 256;
            const int row = idx >> 3, c8 = idx & 7;
            const short8 k8 = *reinterpret_cast<const short8*>(
                &kb[((size_t)bh * Tt + kt * 64 + row) * Dd + c8 * 8]);
            *reinterpret_cast<short8*>(&Ks[row][(c8 ^ (row & 7)) * 8]) = k8;
            const short8 v8 = *reinterpret_cast<const short8*>(
                &vtb[((size_t)bh * Dd + row) * Tt + kt * 64 + c8 * 8]);
            *reinterpret_cast<short8*>(&Vts[row][(c8 ^ (row & 7)) * 8]) = v8;
        }
        __syncthreads();

        // ---- S = Q K^T ----
        f32x4 sacc[4];
        #pragma unroll
        for (int nb = 0; nb < 4; ++nb) {
            const int krow = nb * 16 + l15;
            const int sw = krow & 7;
            const short8 kf0 = *reinterpret_cast<const short8*>(&Ks[krow][((0 + lg) ^ sw) * 8]);
            const short8 kf1 = *reinterpret_cast<const short8*>(&Ks[krow][((4 + lg) ^ sw) * 8]);
            f32x4 z = {0.f, 0.f, 0.f, 0.f};
            z = __builtin_amdgcn_mfma_f32_16x16x32_bf16(qf[0], kf0, z, 0, 0, 0);
            sacc[nb] = __builtin_amdgcn_mfma_f32_16x16x32_bf16(qf[1], kf1, z, 0, 0, 0);
        }

        // ---- scale + causal mask ----
        const int qa = qt * 64 + w * 16 + lg * 4;   // + r
        const bool diag = (kt == qt);
        #pragma unroll
        for (int nb = 0; nb < 4; ++nb) {
            const int ka = kt * 64 + nb * 16 + l15;
            #pragma unroll
            for (int r = 0; r < 4; ++r) {
                float s = sacc[nb][r] * 0.125f;
                if (diag && ka > qa + r) s = -INFINITY;
                sacc[nb][r] = s;
            }
        }

        // ---- online softmax (rows live in 16-lane groups) ----
        float p[4][4];
        #pragma unroll
        for (int r = 0; r < 4; ++r) {
            float tm = fmaxf(fmaxf(sacc[0][r], sacc[1][r]), fmaxf(sacc[2][r], sacc[3][r]));
            tm = fmaxf(tm, __shfl_xor(tm, 1));
            tm = fmaxf(tm, __shfl_xor(tm, 2));
            tm = fmaxf(tm, __shfl_xor(tm, 4));
            tm = fmaxf(tm, __shfl_xor(tm, 8));
            const float mnew = fmaxf(mrow[r], tm);
            const float corr = __expf(mrow[r] - mnew);
            float rs = 0.f;
            #pragma unroll
            for (int nb = 0; nb < 4; ++nb) {
                const float pv = __expf(sacc[nb][r] - mnew);
                p[nb][r] = pv;
                rs += pv;
            }
            rs += __shfl_xor(rs, 1);
            rs += __shfl_xor(rs, 2);
            rs += __shfl_xor(rs, 4);
            rs += __shfl_xor(rs, 8);
            lrow[r] = lrow[r] * corr + rs;
            mrow[r] = mnew;
            #pragma unroll
            for (int jb = 0; jb < 4; ++jb) oacc[jb][r] *= corr;
        }

        // ---- P: C-frag -> per-wave LDS slab (bf16) -> A-frag ----
        #pragma unroll
        for (int nb = 0; nb < 4; ++nb)
            #pragma unroll
            for (int r = 0; r < 4; ++r)
                Ps[w * 16 + lg * 4 + r][nb * 16 + l15] = f2bf(p[nb][r]);

        short8 pf[2];
        {
            const unsigned short* pp = &Ps[w * 16 + l15][lg * 8];
            pf[0] = *reinterpret_cast<const short8*>(pp);
            pf[1] = *reinterpret_cast<const short8*>(pp + 32);
        }

        // ---- O += P V ----
        #pragma unroll
        for (int jb = 0; jb < 4; ++jb) {
            const int vrow = jb * 16 + l15;
            const int sw = vrow & 7;
            const short8 vf0 = *reinterpret_cast<const short8*>(&Vts[vrow][((0 + lg) ^ sw) * 8]);
            const short8 vf1 = *reinterpret_cast<const short8*>(&Vts[vrow][((4 + lg) ^ sw) * 8]);
            oacc[jb] = __builtin_amdgcn_mfma_f32_16x16x32_bf16(pf[0], vf0, oacc[jb], 0, 0, 0);
            oacc[jb] = __builtin_amdgcn_mfma_f32_16x16x32_bf16(pf[1], vf1, oacc[jb], 0, 0, 0);
        }
    }

    // ---- epilogue: normalize, bf16 out in [B,T,C] ----
    const int b_ = bh >> 3, h = bh & 7;
    #pragma unroll
    for (int r = 0; r < 4; ++r) {
        const float inv = 1.f / lrow[r];
        const int t = qt * 64 + w * 16 + lg * 4 + r;
        unsigned short* dst = ob + ((size_t)b_ * Tt + t) * Cc + h * Dd;
        #pragma unroll
        for (int jb = 0; jb < 4; ++jb)
            dst[jb * 16 + l15] = f2bf(oacc[jb][r] * inv);
    }
}

// ---------------------------------------------------------------------------
extern "C" void kernel_launch(void* const* d_in, const int* in_sizes, int n_in,
                              void* d_out, int out_size, void* d_ws, size_t ws_size,
                              hipStream_t stream) {
    const float* x  = (const float*)d_in[0];
    const float* wq = (const float*)d_in[1];
    const float* bq = (const float*)d_in[2];
    const float* wk = (const float*)d_in[3];
    const float* bk = (const float*)d_in[4];
    const float* wv = (const float*)d_in[5];
    const float* bv = (const float*)d_in[6];
    const float* wo = (const float*)d_in[7];
    const float* bo = (const float*)d_in[8];
    float* out = (float*)d_out;

    const size_t nTok = (size_t)Mtot * Cc;       // 4,194,304 elems
    const size_t nW   = (size_t)Cc * Cc;         //   262,144 elems

    unsigned short* xb    = (unsigned short*)d_ws;
    unsigned short* wqb   = xb + nTok;
    unsigned short* wkb   = wqb + nW;
    unsigned short* wvb   = wkb + nW;
    unsigned short* wob   = wvb + nW;
    unsigned short* qbuf  = wob + nW;            // [B,H,T,D] bf16
    unsigned short* kbuf  = qbuf + nTok;
    unsigned short* vbuf  = kbuf + nTok;
    unsigned short* vtbuf = vbuf + nTok;         // [B,H,D,T] bf16
    unsigned short* oattb = vtbuf + nTok;        // [B,T,C]  bf16

    cast_f32_bf16<<<dim3((unsigned)(nTok / 8 / 256)), 256, 0, stream>>>(x, xb);
    cast_w4<<<dim3((unsigned)(nW / 8 / 256), 4), 256, 0, stream>>>(wq, wk, wv, wo, wqb);

    const dim3 gridP(Mtot / 128, Cc / 128);      // 64 x 4
    proj_mfma<0><<<gridP, 256, 0, stream>>>(xb, wqb, bq, qbuf);
    proj_mfma<0><<<gridP, 256, 0, stream>>>(xb, wkb, bk, kbuf);
    proj_mfma<0><<<gridP, 256, 0, stream>>>(xb, wvb, bv, vbuf);

    transpose_v<<<dim3(Tt / 64, Bb * Hh), 256, 0, stream>>>(vbuf, vtbuf);

    attn_mfma<<<dim3(Tt / 64, Bb * Hh), 256, 0, stream>>>(qbuf, kbuf, vtbuf, oattb);

    proj_mfma<1><<<gridP, 256, 0, stream>>>(oattb, wob, bo, (void*)out);
}

// Round 5
// 210.662 us; speedup vs baseline: 21.0746x; 1.3472x over previous
//
#include <hip/hip_runtime.h>
#include <math.h>

static constexpr int Bb = 2;
static constexpr int Tt = 4096;
static constexpr int Cc = 512;
static constexpr int Hh = 8;
static constexpr int Dd = 64;
static constexpr int Mtot = Bb * Tt;   // 8192

typedef __attribute__((ext_vector_type(8)))  short   short8;
typedef __attribute__((ext_vector_type(4)))  float   f32x4;
typedef __attribute__((ext_vector_type(16))) float   f32x16;
typedef __attribute__((ext_vector_type(4)))  unsigned int   uint4v;
typedef __attribute__((ext_vector_type(4)))  unsigned short ushort4v;

// fp32 -> bf16 round-to-nearest-even (finite inputs)
__device__ inline unsigned short f2bf(float f) {
    unsigned int u = __float_as_uint(f);
    u += 0x7fffu + ((u >> 16) & 1u);
    return (unsigned short)(u >> 16);
}

// pack two f32 -> two bf16 in one u32 (low = a, high = b)
__device__ inline unsigned int cvtpk_bf16(float a, float b) {
    unsigned int r;
    asm("v_cvt_pk_bf16_f32 %0, %1, %2" : "=v"(r) : "v"(a), "v"(b));
    return r;
}

// ---------------------------------------------------------------------------
// casts fp32 -> bf16
// ---------------------------------------------------------------------------
__global__ __launch_bounds__(256)
void cast_f32_bf16(const float* __restrict__ src, unsigned short* __restrict__ dst) {
    const size_t i = ((size_t)blockIdx.x * 256 + threadIdx.x) * 8;
    const float4 a = *reinterpret_cast<const float4*>(src + i);
    const float4 b = *reinterpret_cast<const float4*>(src + i + 4);
    short8 o;
    o[0] = (short)f2bf(a.x); o[1] = (short)f2bf(a.y);
    o[2] = (short)f2bf(a.z); o[3] = (short)f2bf(a.w);
    o[4] = (short)f2bf(b.x); o[5] = (short)f2bf(b.y);
    o[6] = (short)f2bf(b.z); o[7] = (short)f2bf(b.w);
    *reinterpret_cast<short8*>(dst + i) = o;
}

__global__ __launch_bounds__(256)
void cast_w4(const float* __restrict__ w0, const float* __restrict__ w1,
             const float* __restrict__ w2, const float* __restrict__ w3,
             unsigned short* __restrict__ dst) {
    const float* srcs[4] = {w0, w1, w2, w3};
    const float* s = srcs[blockIdx.y];
    unsigned short* d = dst + (size_t)blockIdx.y * (Cc * Cc);
    const size_t i = ((size_t)blockIdx.x * 256 + threadIdx.x) * 8;
    const float4 a = *reinterpret_cast<const float4*>(s + i);
    const float4 b = *reinterpret_cast<const float4*>(s + i + 4);
    short8 o;
    o[0] = (short)f2bf(a.x); o[1] = (short)f2bf(a.y);
    o[2] = (short)f2bf(a.z); o[3] = (short)f2bf(a.w);
    o[4] = (short)f2bf(b.x); o[5] = (short)f2bf(b.y);
    o[6] = (short)f2bf(b.z); o[7] = (short)f2bf(b.w);
    *reinterpret_cast<short8*>(d + i) = o;
}

// ---------------------------------------------------------------------------
// bf16 MFMA GEMM: y[m][n] = (sum_k A[m][k]*W[n][k] + bias[n]) * scale
// Tile 128x128, BK=32, 4 waves (2x2), 16x16x32 frags.
// MODE 0: bf16 out, headed [B,H,T,D]   (Q with scale=0.125, K)
// MODE 1: f32 out, flat [m*C + n]      (final)
// MODE 2: bf16 out, headed-transposed [B,H,D,T]  (V), packed 8B stores
// ---------------------------------------------------------------------------
template <int MODE>
__global__ __launch_bounds__(256)
void proj_mfma(const unsigned short* __restrict__ A, const unsigned short* __restrict__ Wb,
               const float* __restrict__ bias, void* __restrict__ outp, float scale) {
    __shared__ unsigned short As[128][32];
    __shared__ unsigned short Bs[128][32];

    const int tid = threadIdx.x;
    const int lane = tid & 63;
    const int w = tid >> 6;
    const int wr = w >> 1, wc = w & 1;
    const int l15 = lane & 15, lg = lane >> 4;
    const int m0 = blockIdx.x * 128, n0 = blockIdx.y * 128;

    f32x4 acc[4][4] = {};

    for (int k0 = 0; k0 < Cc; k0 += 32) {
        #pragma unroll
        for (int i = 0; i < 2; ++i) {
            const int idx = tid + i * 256;
            const int row = idx >> 2, g = idx & 3;
            *reinterpret_cast<short8*>(&As[row][g * 8]) =
                *reinterpret_cast<const short8*>(&A[(size_t)(m0 + row) * Cc + k0 + g * 8]);
            *reinterpret_cast<short8*>(&Bs[row][g * 8]) =
                *reinterpret_cast<const short8*>(&Wb[(size_t)(n0 + row) * Cc + k0 + g * 8]);
        }
        __syncthreads();
        short8 a[4], b[4];
        #pragma unroll
        for (int mi = 0; mi < 4; ++mi)
            a[mi] = *reinterpret_cast<const short8*>(&As[wr * 64 + mi * 16 + l15][lg * 8]);
        #pragma unroll
        for (int nj = 0; nj < 4; ++nj)
            b[nj] = *reinterpret_cast<const short8*>(&Bs[wc * 64 + nj * 16 + l15][lg * 8]);
        #pragma unroll
        for (int mi = 0; mi < 4; ++mi)
            #pragma unroll
            for (int nj = 0; nj < 4; ++nj)
                acc[mi][nj] = __builtin_amdgcn_mfma_f32_16x16x32_bf16(a[mi], b[nj], acc[mi][nj], 0, 0, 0);
        __syncthreads();
    }

    #pragma unroll
    for (int mi = 0; mi < 4; ++mi) {
        #pragma unroll
        for (int nj = 0; nj < 4; ++nj) {
            const int col = n0 + wc * 64 + nj * 16 + l15;
            const float bv = bias[col];
            if (MODE == 2) {
                const int mbase = m0 + wr * 64 + mi * 16 + lg * 4;
                const int b_ = mbase >> 12, t = mbase & (Tt - 1);
                const int h = col >> 6, d = col & 63;
                ushort4v o;
                #pragma unroll
                for (int r = 0; r < 4; ++r)
                    o[r] = f2bf((acc[mi][nj][r] + bv) * scale);
                *reinterpret_cast<ushort4v*>(
                    &((unsigned short*)outp)[(((size_t)b_ * Hh + h) * Dd + d) * Tt + t]) = o;
            } else {
                #pragma unroll
                for (int r = 0; r < 4; ++r) {
                    const int row = m0 + wr * 64 + mi * 16 + lg * 4 + r;
                    const float val = (acc[mi][nj][r] + bv) * scale;
                    if (MODE == 0) {
                        const int b_ = row >> 12, t = row & (Tt - 1);
                        const int h = col >> 6, d = col & 63;
                        ((unsigned short*)outp)[(((size_t)b_ * Hh + h) * Tt + t) * Dd + d] = f2bf(val);
                    } else {
                        ((float*)outp)[(size_t)row * Cc + col] = val;
                    }
                }
            }
        }
    }
}

// ---------------------------------------------------------------------------
// Causal flash attention, swapped-QK 32x32 MFMA, in-register softmax.
// Block = 4 waves x 32 q-rows (BQ=128), KV tile 64.
// S^T = mfma(K, Q): lane holds one q-row (q = lane&31), kv = (reg&3)+8*(reg>>2)+4*hi.
// Softmax in-register + one permlane32_swap; defer-max THR=8 (T13);
// P -> PV A-frag via cvt_pk_bf16 + permlane32_swap (T12). O: 32q x 64d per wave.
// grid = (32 descending-qt, B*H).
// ---------------------------------------------------------------------------
__global__ __launch_bounds__(256)
void attn_mfma(const unsigned short* __restrict__ qb, const unsigned short* __restrict__ kb,
               const unsigned short* __restrict__ vtb, unsigned short* __restrict__ ob) {
    __shared__ unsigned short Ks[64][64];    // [kv][d], 16B-granule XOR swizzle
    __shared__ unsigned short Vts[64][64];   // [d][kv], 16B-granule XOR swizzle
    __shared__ float stats[4][32];           // per-wave corr / 1/l broadcast

    const int qt = 31 - (int)blockIdx.x;     // long blocks first
    const int bh = blockIdx.y;
    const int tid = threadIdx.x;
    const int w = tid >> 6;
    const int lane = tid & 63;
    const int l31 = lane & 31, hi = lane >> 5;

    const int qg = qt * 128 + w * 32 + l31;  // this lane's q row (global)

    // Q fragments (B-operand: n = l31 = q, k = hi*8+e, slices s*16). Pre-scaled 1/8.
    short8 qf[4];
    {
        const unsigned short* qp = qb + ((size_t)bh * Tt + qg) * Dd + hi * 8;
        #pragma unroll
        for (int s = 0; s < 4; ++s)
            qf[s] = *reinterpret_cast<const short8*>(qp + s * 16);
    }

    f32x16 oacc[2] = {};
    float mrow = -INFINITY, lrow = 0.f;
    const f32x16 zero16 = {};

    const int ntiles = 2 * qt + 2;
    const int qmax_w = qt * 128 + w * 32 + 31;
    const int qmin_w = qt * 128 + w * 32;

    for (int kt = 0; kt < ntiles; ++kt) {
        __syncthreads();   // prev tile's frag reads complete
        #pragma unroll
        for (int i = 0; i < 2; ++i) {
            const int idx = tid + i * 256;
            const int row = idx >> 3, c8 = idx & 7;
            const short8 k8 = *reinterpret_cast<const short8*>(
                &kb[((size_t)bh * Tt + kt * 64 + row) * Dd + c8 * 8]);
            *reinterpret_cast<short8*>(&Ks[row][(c8 ^ (row & 7)) * 8]) = k8;
            const short8 v8 = *reinterpret_cast<const short8*>(
                &vtb[((size_t)bh * Dd + row) * Tt + kt * 64 + c8 * 8]);
            *reinterpret_cast<short8*>(&Vts[row][(c8 ^ (row & 7)) * 8]) = v8;
        }
        __syncthreads();

        if (kt * 64 > qmax_w) continue;   // beyond causal limit for this wave

        // ---- S^T = K Q^T : sacc[f][reg] = S[kv][q], kv=(reg&3)+8*(reg>>2)+4*hi+32f
        f32x16 sacc[2];
        #pragma unroll
        for (int f = 0; f < 2; ++f) {
            f32x16 z = zero16;
            const int krow = f * 32 + l31;
            const int sw = krow & 7;
            #pragma unroll
            for (int s = 0; s < 4; ++s) {
                const short8 kf = *reinterpret_cast<const short8*>(
                    &Ks[krow][((2 * s + hi) ^ sw) * 8]);
                z = __builtin_amdgcn_mfma_f32_32x32x16_bf16(kf, qf[s], z, 0, 0, 0);
            }
            sacc[f] = z;
        }

        // ---- causal mask (only tiles crossing this wave's diagonal) ----
        if (kt * 64 + 63 > qmin_w) {
            #pragma unroll
            for (int f = 0; f < 2; ++f)
                #pragma unroll
                for (int r = 0; r < 16; ++r) {
                    const int kvg = kt * 64 + f * 32 + (r & 3) + 8 * (r >> 2) + 4 * hi;
                    if (kvg > qg) sacc[f][r] = -INFINITY;
                }
        }

        // ---- row max (in-register + one cross-half) ----
        float pmax = sacc[0][0];
        #pragma unroll
        for (int r = 1; r < 16; ++r) pmax = fmaxf(pmax, sacc[0][r]);
        #pragma unroll
        for (int r = 0; r < 16; ++r) pmax = fmaxf(pmax, sacc[1][r]);
        pmax = fmaxf(pmax, __shfl_xor(pmax, 32));

        // ---- defer-max: rescale only when max grew past THR=8 ----
        if (__any(pmax > mrow + 8.f)) {
            const float mnew = fmaxf(mrow, pmax);
            const float corr = __expf(mrow - mnew);   // 0 on first tile
            mrow = mnew;
            lrow *= corr;
            stats[w][l31] = corr;                     // hi duplicate: same value
            #pragma unroll
            for (int r = 0; r < 16; ++r) {
                const float c = stats[w][(r & 3) + 8 * (r >> 2) + 4 * hi];
                oacc[0][r] *= c;
                oacc[1][r] *= c;
            }
        }

        // ---- P = exp(S - m), row sum ----
        float rs = 0.f;
        #pragma unroll
        for (int f = 0; f < 2; ++f)
            #pragma unroll
            for (int r = 0; r < 16; ++r) {
                const float p = __expf(sacc[f][r] - mrow);
                sacc[f][r] = p;
                rs += p;
            }
        lrow += rs;

        // ---- P -> bf16 A-frags (cvt_pk + permlane32_swap) and O += P V ----
        #pragma unroll
        for (int f = 0; f < 2; ++f) {
            #pragma unroll
            for (int s2 = 0; s2 < 2; ++s2) {
                const int b0 = s2 * 8;
                unsigned int c01 = cvtpk_bf16(sacc[f][b0 + 0], sacc[f][b0 + 1]);
                unsigned int c23 = cvtpk_bf16(sacc[f][b0 + 2], sacc[f][b0 + 3]);
                unsigned int c45 = cvtpk_bf16(sacc[f][b0 + 4], sacc[f][b0 + 5]);
                unsigned int c67 = cvtpk_bf16(sacc[f][b0 + 6], sacc[f][b0 + 7]);
                asm("v_permlane32_swap_b32 %0, %1" : "+v"(c01), "+v"(c45));
                asm("v_permlane32_swap_b32 %0, %1" : "+v"(c23), "+v"(c67));
                uint4v paw;
                paw[0] = c01; paw[1] = c23; paw[2] = c45; paw[3] = c67;
                const short8 pa = *reinterpret_cast<short8*>(&paw);
                const int g = 4 * f + 2 * s2;
                #pragma unroll
                for (int nb = 0; nb < 2; ++nb) {
                    const int vrow = nb * 32 + l31;
                    const short8 vf = *reinterpret_cast<const short8*>(
                        &Vts[vrow][((g + hi) ^ (vrow & 7)) * 8]);
                    oacc[nb] = __builtin_amdgcn_mfma_f32_32x32x16_bf16(pa, vf, oacc[nb], 0, 0, 0);
                }
            }
        }
    }

    // ---- epilogue: 1/l broadcast, normalize, bf16 out in [B,T,C] ----
    const float lf = lrow + __shfl_xor(lrow, 32);
    stats[w][l31] = 1.f / lf;
    const int b_ = bh >> 3, h = bh & 7;
    #pragma unroll
    for (int r = 0; r < 16; ++r) {
        const int qr = (r & 3) + 8 * (r >> 2) + 4 * hi;
        const float linv = stats[w][qr];
        const int tg = qt * 128 + w * 32 + qr;
        unsigned short* dst = ob + ((size_t)b_ * Tt + tg) * Cc + h * Dd + l31;
        dst[0]  = f2bf(oacc[0][r] * linv);
        dst[32] = f2bf(oacc[1][r] * linv);
    }
}

// ---------------------------------------------------------------------------
extern "C" void kernel_launch(void* const* d_in, const int* in_sizes, int n_in,
                              void* d_out, int out_size, void* d_ws, size_t ws_size,
                              hipStream_t stream) {
    const float* x  = (const float*)d_in[0];
    const float* wq = (const float*)d_in[1];
    const float* bq = (const float*)d_in[2];
    const float* wk = (const float*)d_in[3];
    const float* bk = (const float*)d_in[4];
    const float* wv = (const float*)d_in[5];
    const float* bv = (const float*)d_in[6];
    const float* wo = (const float*)d_in[7];
    const float* bo = (const float*)d_in[8];
    float* out = (float*)d_out;

    const size_t nTok = (size_t)Mtot * Cc;       // 4,194,304 elems
    const size_t nW   = (size_t)Cc * Cc;

    unsigned short* xb    = (unsigned short*)d_ws;
    unsigned short* wqb   = xb + nTok;
    unsigned short* wkb   = wqb + nW;
    unsigned short* wvb   = wkb + nW;
    unsigned short* wob   = wvb + nW;
    unsigned short* qbuf  = wob + nW;            // [B,H,T,D] bf16 (pre-scaled 1/8)
    unsigned short* kbuf  = qbuf + nTok;         // [B,H,T,D] bf16
    unsigned short* vtbuf = kbuf + nTok;         // [B,H,D,T] bf16
    unsigned short* oattb = vtbuf + nTok;        // [B,T,C]  bf16

    cast_f32_bf16<<<dim3((unsigned)(nTok / 8 / 256)), 256, 0, stream>>>(x, xb);
    cast_w4<<<dim3((unsigned)(nW / 8 / 256), 4), 256, 0, stream>>>(wq, wk, wv, wo, wqb);

    const dim3 gridP(Mtot / 128, Cc / 128);      // 64 x 4
    proj_mfma<0><<<gridP, 256, 0, stream>>>(xb, wqb, bq, qbuf, 0.125f);
    proj_mfma<0><<<gridP, 256, 0, stream>>>(xb, wkb, bk, kbuf, 1.0f);
    proj_mfma<2><<<gridP, 256, 0, stream>>>(xb, wvb, bv, vtbuf, 1.0f);

    attn_mfma<<<dim3(32, Bb * Hh), 256, 0, stream>>>(qbuf, kbuf, vtbuf, oattb);

    proj_mfma<1><<<gridP, 256, 0, stream>>>(oattb, wob, bo, (void*)out, 1.0f);
}

// Round 6
// 195.465 us; speedup vs baseline: 22.7131x; 1.0777x over previous
//
#include <hip/hip_runtime.h>
#include <math.h>

static constexpr int Bb = 2;
static constexpr int Tt = 4096;
static constexpr int Cc = 512;
static constexpr int Hh = 8;
static constexpr int Dd = 64;
static constexpr int Mtot = Bb * Tt;   // 8192

// Q pre-scale: 1/sqrt(64) * log2(e)  (softmax done in exp2 units)
#define QSCALE 0.1803368801111f
#define DEFER_THR 11.5f                // == e^8 bound in exp2 units

typedef __attribute__((ext_vector_type(8)))  short   short8;
typedef __attribute__((ext_vector_type(4)))  float   f32x4;
typedef __attribute__((ext_vector_type(16))) float   f32x16;
typedef __attribute__((ext_vector_type(4)))  unsigned int   uint4v;
typedef __attribute__((ext_vector_type(4)))  unsigned short ushort4v;

__device__ inline unsigned short f2bf(float f) {
    unsigned int u = __float_as_uint(f);
    u += 0x7fffu + ((u >> 16) & 1u);
    return (unsigned short)(u >> 16);
}

__device__ inline unsigned int cvtpk_bf16(float a, float b) {
    unsigned int r;
    asm("v_cvt_pk_bf16_f32 %0, %1, %2" : "=v"(r) : "v"(a), "v"(b));
    return r;
}

// full-row LDS granule swizzle (16B granules, 8 per 128B row)
__device__ inline int SW(int row) { return (row ^ (row >> 3)) & 7; }

// ---------------------------------------------------------------------------
// casts fp32 -> bf16
// ---------------------------------------------------------------------------
__global__ __launch_bounds__(256)
void cast_f32_bf16(const float* __restrict__ src, unsigned short* __restrict__ dst) {
    const size_t i = ((size_t)blockIdx.x * 256 + threadIdx.x) * 8;
    const float4 a = *reinterpret_cast<const float4*>(src + i);
    const float4 b = *reinterpret_cast<const float4*>(src + i + 4);
    short8 o;
    o[0] = (short)f2bf(a.x); o[1] = (short)f2bf(a.y);
    o[2] = (short)f2bf(a.z); o[3] = (short)f2bf(a.w);
    o[4] = (short)f2bf(b.x); o[5] = (short)f2bf(b.y);
    o[6] = (short)f2bf(b.z); o[7] = (short)f2bf(b.w);
    *reinterpret_cast<short8*>(dst + i) = o;
}

__global__ __launch_bounds__(256)
void cast_w4(const float* __restrict__ w0, const float* __restrict__ w1,
             const float* __restrict__ w2, const float* __restrict__ w3,
             unsigned short* __restrict__ dst) {
    const float* srcs[4] = {w0, w1, w2, w3};
    const float* s = srcs[blockIdx.y];
    unsigned short* d = dst + (size_t)blockIdx.y * (Cc * Cc);
    const size_t i = ((size_t)blockIdx.x * 256 + threadIdx.x) * 8;
    const float4 a = *reinterpret_cast<const float4*>(s + i);
    const float4 b = *reinterpret_cast<const float4*>(s + i + 4);
    short8 o;
    o[0] = (short)f2bf(a.x); o[1] = (short)f2bf(a.y);
    o[2] = (short)f2bf(a.z); o[3] = (short)f2bf(a.w);
    o[4] = (short)f2bf(b.x); o[5] = (short)f2bf(b.y);
    o[6] = (short)f2bf(b.z); o[7] = (short)f2bf(b.w);
    *reinterpret_cast<short8*>(d + i) = o;
}

// ---------------------------------------------------------------------------
// Fused Q/K/V projection. blockIdx.z = which (0=Q, 1=K, 2=V).
// Tile 128x128, BK=32, 4 waves, 16x16x32 frags.
// Q: bf16 headed [B,H,T,D], scaled QSCALE. K: same, scale 1.
// V: bf16 headed-TRANSPOSED [B,H,D,T] (packed 8B stores).
// ---------------------------------------------------------------------------
__global__ __launch_bounds__(256)
void proj_qkv(const unsigned short* __restrict__ A, const unsigned short* __restrict__ Wall,
              const float* __restrict__ bq, const float* __restrict__ bk,
              const float* __restrict__ bv,
              unsigned short* __restrict__ qo, unsigned short* __restrict__ ko,
              unsigned short* __restrict__ vo) {
    __shared__ unsigned short As[128][32];
    __shared__ unsigned short Bs[128][32];

    const int which = blockIdx.z;
    const unsigned short* Wb = Wall + (size_t)which * Cc * Cc;
    const float* bias = (which == 0) ? bq : (which == 1) ? bk : bv;
    unsigned short* outp = (which == 0) ? qo : (which == 1) ? ko : vo;
    const float scale = (which == 0) ? QSCALE : 1.0f;

    const int tid = threadIdx.x;
    const int lane = tid & 63;
    const int w = tid >> 6;
    const int wr = w >> 1, wc = w & 1;
    const int l15 = lane & 15, lg = lane >> 4;
    const int m0 = blockIdx.x * 128, n0 = blockIdx.y * 128;

    f32x4 acc[4][4] = {};

    for (int k0 = 0; k0 < Cc; k0 += 32) {
        #pragma unroll
        for (int i = 0; i < 2; ++i) {
            const int idx = tid + i * 256;
            const int row = idx >> 2, g = idx & 3;
            *reinterpret_cast<short8*>(&As[row][g * 8]) =
                *reinterpret_cast<const short8*>(&A[(size_t)(m0 + row) * Cc + k0 + g * 8]);
            *reinterpret_cast<short8*>(&Bs[row][g * 8]) =
                *reinterpret_cast<const short8*>(&Wb[(size_t)(n0 + row) * Cc + k0 + g * 8]);
        }
        __syncthreads();
        short8 a[4], b[4];
        #pragma unroll
        for (int mi = 0; mi < 4; ++mi)
            a[mi] = *reinterpret_cast<const short8*>(&As[wr * 64 + mi * 16 + l15][lg * 8]);
        #pragma unroll
        for (int nj = 0; nj < 4; ++nj)
            b[nj] = *reinterpret_cast<const short8*>(&Bs[wc * 64 + nj * 16 + l15][lg * 8]);
        #pragma unroll
        for (int mi = 0; mi < 4; ++mi)
            #pragma unroll
            for (int nj = 0; nj < 4; ++nj)
                acc[mi][nj] = __builtin_amdgcn_mfma_f32_16x16x32_bf16(a[mi], b[nj], acc[mi][nj], 0, 0, 0);
        __syncthreads();
    }

    #pragma unroll
    for (int mi = 0; mi < 4; ++mi) {
        #pragma unroll
        for (int nj = 0; nj < 4; ++nj) {
            const int col = n0 + wc * 64 + nj * 16 + l15;
            const float bvv = bias[col];
            if (which == 2) {
                const int mbase = m0 + wr * 64 + mi * 16 + lg * 4;
                const int b_ = mbase >> 12, t = mbase & (Tt - 1);
                const int h = col >> 6, d = col & 63;
                ushort4v o;
                #pragma unroll
                for (int r = 0; r < 4; ++r)
                    o[r] = f2bf(acc[mi][nj][r] + bvv);
                *reinterpret_cast<ushort4v*>(
                    &outp[(((size_t)b_ * Hh + h) * Dd + d) * Tt + t]) = o;
            } else {
                #pragma unroll
                for (int r = 0; r < 4; ++r) {
                    const int row = m0 + wr * 64 + mi * 16 + lg * 4 + r;
                    const int b_ = row >> 12, t = row & (Tt - 1);
                    const int h = col >> 6, d = col & 63;
                    outp[(((size_t)b_ * Hh + h) * Tt + t) * Dd + d] =
                        f2bf((acc[mi][nj][r] + bvv) * scale);
                }
            }
        }
    }
}

// ---------------------------------------------------------------------------
// Output projection: f32 out, flat [m*C + n]
// ---------------------------------------------------------------------------
__global__ __launch_bounds__(256)
void proj_out(const unsigned short* __restrict__ A, const unsigned short* __restrict__ Wb,
              const float* __restrict__ bias, float* __restrict__ outp) {
    __shared__ unsigned short As[128][32];
    __shared__ unsigned short Bs[128][32];

    const int tid = threadIdx.x;
    const int lane = tid & 63;
    const int w = tid >> 6;
    const int wr = w >> 1, wc = w & 1;
    const int l15 = lane & 15, lg = lane >> 4;
    const int m0 = blockIdx.x * 128, n0 = blockIdx.y * 128;

    f32x4 acc[4][4] = {};

    for (int k0 = 0; k0 < Cc; k0 += 32) {
        #pragma unroll
        for (int i = 0; i < 2; ++i) {
            const int idx = tid + i * 256;
            const int row = idx >> 2, g = idx & 3;
            *reinterpret_cast<short8*>(&As[row][g * 8]) =
                *reinterpret_cast<const short8*>(&A[(size_t)(m0 + row) * Cc + k0 + g * 8]);
            *reinterpret_cast<short8*>(&Bs[row][g * 8]) =
                *reinterpret_cast<const short8*>(&Wb[(size_t)(n0 + row) * Cc + k0 + g * 8]);
        }
        __syncthreads();
        short8 a[4], b[4];
        #pragma unroll
        for (int mi = 0; mi < 4; ++mi)
            a[mi] = *reinterpret_cast<const short8*>(&As[wr * 64 + mi * 16 + l15][lg * 8]);
        #pragma unroll
        for (int nj = 0; nj < 4; ++nj)
            b[nj] = *reinterpret_cast<const short8*>(&Bs[wc * 64 + nj * 16 + l15][lg * 8]);
        #pragma unroll
        for (int mi = 0; mi < 4; ++mi)
            #pragma unroll
            for (int nj = 0; nj < 4; ++nj)
                acc[mi][nj] = __builtin_amdgcn_mfma_f32_16x16x32_bf16(a[mi], b[nj], acc[mi][nj], 0, 0, 0);
        __syncthreads();
    }

    #pragma unroll
    for (int mi = 0; mi < 4; ++mi) {
        #pragma unroll
        for (int nj = 0; nj < 4; ++nj) {
            const int col = n0 + wc * 64 + nj * 16 + l15;
            const float bv = bias[col];
            #pragma unroll
            for (int r = 0; r < 4; ++r) {
                const int row = m0 + wr * 64 + mi * 16 + lg * 4 + r;
                outp[(size_t)row * Cc + col] = acc[mi][nj][r] + bv;
            }
        }
    }
}

// ---------------------------------------------------------------------------
// Causal flash attention, swapped-QK 32x32 MFMA, in-register softmax (exp2).
// Double-buffered LDS, async global->reg->LDS staging, ONE barrier per tile.
// Block = 4 waves x 32 q-rows (BQ=128), KV tile 64. Full-row XOR swizzle SW().
// grid = (32 descending-qt, B*H).
// ---------------------------------------------------------------------------
__global__ __launch_bounds__(256)
void attn_mfma(const unsigned short* __restrict__ qb, const unsigned short* __restrict__ kb,
               const unsigned short* __restrict__ vtb, unsigned short* __restrict__ ob) {
    __shared__ unsigned short Ks[2][64][64];    // [buf][kv][d]
    __shared__ unsigned short Vts[2][64][64];   // [buf][d][kv]
    __shared__ float stats[4][32];

    const int qt = 31 - (int)blockIdx.x;     // long blocks first
    const int bh = blockIdx.y;
    const int tid = threadIdx.x;
    const int w = tid >> 6;
    const int lane = tid & 63;
    const int l31 = lane & 31, hi = lane >> 5;

    const int qg = qt * 128 + w * 32 + l31;

    // Q fragments (B-operand), pre-scaled QSCALE at projection
    short8 qf[4];
    {
        const unsigned short* qp = qb + ((size_t)bh * Tt + qg) * Dd + hi * 8;
        #pragma unroll
        for (int s = 0; s < 4; ++s)
            qf[s] = *reinterpret_cast<const short8*>(qp + s * 16);
    }

    // staging geometry: each thread owns rows (srow, srow+32) x granule sc8
    const int srow = tid >> 3;              // 0..31
    const int sc8  = tid & 7;
    const unsigned short* kb_h = kb + (size_t)bh * Tt * Dd;
    const unsigned short* vt_h = vtb + (size_t)bh * Dd * Tt;
    const int g0 = (sc8 ^ SW(srow)) * 8;
    const int g1 = (sc8 ^ SW(srow + 32)) * 8;

    short8 kreg0, kreg1, vreg0, vreg1;

    f32x16 oacc[2] = {};
    float mrow = -INFINITY, lrow = 0.f;

    const int ntiles = 2 * qt + 2;
    const int qmax_w = qt * 128 + w * 32 + 31;
    const int qmin_w = qt * 128 + w * 32;

    // ---- prologue: stage tile 0 into buf 0 ----
    {
        kreg0 = *reinterpret_cast<const short8*>(&kb_h[(size_t)srow * Dd + sc8 * 8]);
        kreg1 = *reinterpret_cast<const short8*>(&kb_h[(size_t)(srow + 32) * Dd + sc8 * 8]);
        vreg0 = *reinterpret_cast<const short8*>(&vt_h[(size_t)srow * Tt + sc8 * 8]);
        vreg1 = *reinterpret_cast<const short8*>(&vt_h[(size_t)(srow + 32) * Tt + sc8 * 8]);
        *reinterpret_cast<short8*>(&Ks[0][srow][g0]) = kreg0;
        *reinterpret_cast<short8*>(&Ks[0][srow + 32][g1]) = kreg1;
        *reinterpret_cast<short8*>(&Vts[0][srow][g0]) = vreg0;
        *reinterpret_cast<short8*>(&Vts[0][srow + 32][g1]) = vreg1;
    }
    __syncthreads();

    for (int kt = 0; kt < ntiles; ++kt) {
        const int cur = kt & 1;
        const bool more = (kt + 1 < ntiles);

        // ---- issue next tile's loads (latency hidden under compute) ----
        if (more) {
            const int n64 = (kt + 1) * 64;
            kreg0 = *reinterpret_cast<const short8*>(&kb_h[(size_t)(n64 + srow) * Dd + sc8 * 8]);
            kreg1 = *reinterpret_cast<const short8*>(&kb_h[(size_t)(n64 + srow + 32) * Dd + sc8 * 8]);
            vreg0 = *reinterpret_cast<const short8*>(&vt_h[(size_t)srow * Tt + n64 + sc8 * 8]);
            vreg1 = *reinterpret_cast<const short8*>(&vt_h[(size_t)(srow + 32) * Tt + n64 + sc8 * 8]);
        }

        if (kt * 64 <= qmax_w) {
            // ---- S^T = K Q^T : sacc[f][reg]=S[kv][q], kv=(r&3)+8*(r>>2)+4*hi+32f
            f32x16 sacc[2];
            #pragma unroll
            for (int f = 0; f < 2; ++f) {
                f32x16 z = {};
                const int krow = f * 32 + l31;
                const int sw = SW(krow);
                #pragma unroll
                for (int s = 0; s < 4; ++s) {
                    const short8 kf = *reinterpret_cast<const short8*>(
                        &Ks[cur][krow][((2 * s + hi) ^ sw) * 8]);
                    z = __builtin_amdgcn_mfma_f32_32x32x16_bf16(kf, qf[s], z, 0, 0, 0);
                }
                sacc[f] = z;
            }

            // ---- causal mask ----
            if (kt * 64 + 63 > qmin_w) {
                #pragma unroll
                for (int f = 0; f < 2; ++f)
                    #pragma unroll
                    for (int r = 0; r < 16; ++r) {
                        const int kvg = kt * 64 + f * 32 + (r & 3) + 8 * (r >> 2) + 4 * hi;
                        if (kvg > qg) sacc[f][r] = -INFINITY;
                    }
            }

            // ---- row max ----
            float pmax = sacc[0][0];
            #pragma unroll
            for (int r = 1; r < 16; ++r) pmax = fmaxf(pmax, sacc[0][r]);
            #pragma unroll
            for (int r = 0; r < 16; ++r) pmax = fmaxf(pmax, sacc[1][r]);
            pmax = fmaxf(pmax, __shfl_xor(pmax, 32));

            // ---- defer-max rescale ----
            if (__any(pmax > mrow + DEFER_THR)) {
                const float mnew = fmaxf(mrow, pmax);
                const float corr = exp2f(mrow - mnew);
                mrow = mnew;
                lrow *= corr;
                stats[w][l31] = corr;
                #pragma unroll
                for (int r = 0; r < 16; ++r) {
                    const float c = stats[w][(r & 3) + 8 * (r >> 2) + 4 * hi];
                    oacc[0][r] *= c;
                    oacc[1][r] *= c;
                }
            }

            // ---- P = exp2(S - m), row sum ----
            float rs = 0.f;
            #pragma unroll
            for (int f = 0; f < 2; ++f)
                #pragma unroll
                for (int r = 0; r < 16; ++r) {
                    const float p = exp2f(sacc[f][r] - mrow);
                    sacc[f][r] = p;
                    rs += p;
                }
            lrow += rs;

            // ---- P -> bf16 A-frags (cvt_pk + permlane32_swap); O += P V ----
            #pragma unroll
            for (int f = 0; f < 2; ++f) {
                #pragma unroll
                for (int s2 = 0; s2 < 2; ++s2) {
                    const int b0 = s2 * 8;
                    unsigned int c01 = cvtpk_bf16(sacc[f][b0 + 0], sacc[f][b0 + 1]);
                    unsigned int c23 = cvtpk_bf16(sacc[f][b0 + 2], sacc[f][b0 + 3]);
                    unsigned int c45 = cvtpk_bf16(sacc[f][b0 + 4], sacc[f][b0 + 5]);
                    unsigned int c67 = cvtpk_bf16(sacc[f][b0 + 6], sacc[f][b0 + 7]);
                    asm("v_permlane32_swap_b32 %0, %1" : "+v"(c01), "+v"(c45));
                    asm("v_permlane32_swap_b32 %0, %1" : "+v"(c23), "+v"(c67));
                    uint4v paw;
                    paw[0] = c01; paw[1] = c23; paw[2] = c45; paw[3] = c67;
                    const short8 pa = *reinterpret_cast<short8*>(&paw);
                    const int g = 4 * f + 2 * s2;
                    #pragma unroll
                    for (int nb = 0; nb < 2; ++nb) {
                        const int vrow = nb * 32 + l31;
                        const short8 vf = *reinterpret_cast<const short8*>(
                            &Vts[cur][vrow][((g + hi) ^ SW(vrow)) * 8]);
                        oacc[nb] = __builtin_amdgcn_mfma_f32_32x32x16_bf16(pa, vf, oacc[nb], 0, 0, 0);
                    }
                }
            }
        }

        // ---- write staged regs into the other buffer ----
        if (more) {
            const int nxt = cur ^ 1;
            *reinterpret_cast<short8*>(&Ks[nxt][srow][g0]) = kreg0;
            *reinterpret_cast<short8*>(&Ks[nxt][srow + 32][g1]) = kreg1;
            *reinterpret_cast<short8*>(&Vts[nxt][srow][g0]) = vreg0;
            *reinterpret_cast<short8*>(&Vts[nxt][srow + 32][g1]) = vreg1;
        }
        __syncthreads();
    }

    // ---- epilogue ----
    const float lf = lrow + __shfl_xor(lrow, 32);
    stats[w][l31] = 1.f / lf;
    const int b_ = bh >> 3, h = bh & 7;
    #pragma unroll
    for (int r = 0; r < 16; ++r) {
        const int qr = (r & 3) + 8 * (r >> 2) + 4 * hi;
        const float linv = stats[w][qr];
        const int tg = qt * 128 + w * 32 + qr;
        unsigned short* dst = ob + ((size_t)b_ * Tt + tg) * Cc + h * Dd + l31;
        dst[0]  = f2bf(oacc[0][r] * linv);
        dst[32] = f2bf(oacc[1][r] * linv);
    }
}

// ---------------------------------------------------------------------------
extern "C" void kernel_launch(void* const* d_in, const int* in_sizes, int n_in,
                              void* d_out, int out_size, void* d_ws, size_t ws_size,
                              hipStream_t stream) {
    const float* x  = (const float*)d_in[0];
    const float* wq = (const float*)d_in[1];
    const float* bq = (const float*)d_in[2];
    const float* wk = (const float*)d_in[3];
    const float* bk = (const float*)d_in[4];
    const float* wv = (const float*)d_in[5];
    const float* bv = (const float*)d_in[6];
    const float* wo = (const float*)d_in[7];
    const float* bo = (const float*)d_in[8];
    float* out = (float*)d_out;

    const size_t nTok = (size_t)Mtot * Cc;
    const size_t nW   = (size_t)Cc * Cc;

    unsigned short* xb    = (unsigned short*)d_ws;
    unsigned short* wqb   = xb + nTok;           // wq,wk,wv,wo consecutive
    unsigned short* wob   = wqb + 3 * nW;
    unsigned short* qbuf  = wqb + 4 * nW;        // [B,H,T,D] bf16 (pre-scaled)
    unsigned short* kbuf  = qbuf + nTok;         // [B,H,T,D] bf16
    unsigned short* vtbuf = kbuf + nTok;         // [B,H,D,T] bf16
    unsigned short* oattb = vtbuf + nTok;        // [B,T,C]  bf16

    cast_f32_bf16<<<dim3((unsigned)(nTok / 8 / 256)), 256, 0, stream>>>(x, xb);
    cast_w4<<<dim3((unsigned)(nW / 8 / 256), 4), 256, 0, stream>>>(wq, wk, wv, wo, wqb);

    proj_qkv<<<dim3(Mtot / 128, Cc / 128, 3), 256, 0, stream>>>(
        xb, wqb, bq, bk, bv, qbuf, kbuf, vtbuf);

    attn_mfma<<<dim3(32, Bb * Hh), 256, 0, stream>>>(qbuf, kbuf, vtbuf, oattb);

    proj_out<<<dim3(Mtot / 128, Cc / 128), 256, 0, stream>>>(oattb, wob, bo, out);
}

// Round 7
// 164.304 us; speedup vs baseline: 27.0208x; 1.1897x over previous
//
#include <hip/hip_runtime.h>
#include <math.h>

static constexpr int Bb = 2;
static constexpr int Tt = 4096;
static constexpr int Cc = 512;
static constexpr int Hh = 8;
static constexpr int Dd = 64;
static constexpr int Mtot = Bb * Tt;   // 8192

// Q pre-scale: 1/sqrt(64) * log2(e)  (softmax done in exp2 units)
#define QSCALE 0.1803368801111f
#define DEFER_THR 11.5f                // == e^8 bound in exp2 units

typedef __attribute__((ext_vector_type(8)))  short   short8;
typedef __attribute__((ext_vector_type(4)))  float   f32x4;
typedef __attribute__((ext_vector_type(16))) float   f32x16;
typedef __attribute__((ext_vector_type(4)))  unsigned int   uint4v;
typedef __attribute__((ext_vector_type(4)))  unsigned short ushort4v;

__device__ inline unsigned short f2bf(float f) {
    unsigned int u = __float_as_uint(f);
    u += 0x7fffu + ((u >> 16) & 1u);
    return (unsigned short)(u >> 16);
}

__device__ inline unsigned int cvtpk_bf16(float a, float b) {
    unsigned int r;
    asm("v_cvt_pk_bf16_f32 %0, %1, %2" : "=v"(r) : "v"(a), "v"(b));
    return r;
}

// full-row LDS granule swizzle (16B granules, 8 per 128B row)
__device__ inline int SW(int row) { return (row ^ (row >> 3)) & 7; }

// async global -> LDS, 16B per lane. lds must be wave-uniform; g is per-lane.
__device__ inline void gload16(const void* g, void* lds) {
    __builtin_amdgcn_global_load_lds(
        (const __attribute__((address_space(1))) void*)g,
        (__attribute__((address_space(3))) void*)lds, 16, 0, 0);
}

// ---------------------------------------------------------------------------
// casts fp32 -> bf16
// ---------------------------------------------------------------------------
__global__ __launch_bounds__(256)
void cast_f32_bf16(const float* __restrict__ src, unsigned short* __restrict__ dst) {
    const size_t i = ((size_t)blockIdx.x * 256 + threadIdx.x) * 8;
    const float4 a = *reinterpret_cast<const float4*>(src + i);
    const float4 b = *reinterpret_cast<const float4*>(src + i + 4);
    short8 o;
    o[0] = (short)f2bf(a.x); o[1] = (short)f2bf(a.y);
    o[2] = (short)f2bf(a.z); o[3] = (short)f2bf(a.w);
    o[4] = (short)f2bf(b.x); o[5] = (short)f2bf(b.y);
    o[6] = (short)f2bf(b.z); o[7] = (short)f2bf(b.w);
    *reinterpret_cast<short8*>(dst + i) = o;
}

__global__ __launch_bounds__(256)
void cast_w4(const float* __restrict__ w0, const float* __restrict__ w1,
             const float* __restrict__ w2, const float* __restrict__ w3,
             unsigned short* __restrict__ dst) {
    const float* srcs[4] = {w0, w1, w2, w3};
    const float* s = srcs[blockIdx.y];
    unsigned short* d = dst + (size_t)blockIdx.y * (Cc * Cc);
    const size_t i = ((size_t)blockIdx.x * 256 + threadIdx.x) * 8;
    const float4 a = *reinterpret_cast<const float4*>(s + i);
    const float4 b = *reinterpret_cast<const float4*>(s + i + 4);
    short8 o;
    o[0] = (short)f2bf(a.x); o[1] = (short)f2bf(a.y);
    o[2] = (short)f2bf(a.z); o[3] = (short)f2bf(a.w);
    o[4] = (short)f2bf(b.x); o[5] = (short)f2bf(b.y);
    o[6] = (short)f2bf(b.z); o[7] = (short)f2bf(b.w);
    *reinterpret_cast<short8*>(d + i) = o;
}

// ---------------------------------------------------------------------------
// Fused Q/K/V projection. blockIdx.z = which (0=Q, 1=K, 2=V).
// ---------------------------------------------------------------------------
__global__ __launch_bounds__(256)
void proj_qkv(const unsigned short* __restrict__ A, const unsigned short* __restrict__ Wall,
              const float* __restrict__ bq, const float* __restrict__ bk,
              const float* __restrict__ bv,
              unsigned short* __restrict__ qo, unsigned short* __restrict__ ko,
              unsigned short* __restrict__ vo) {
    __shared__ unsigned short As[128][32];
    __shared__ unsigned short Bs[128][32];

    const int which = blockIdx.z;
    const unsigned short* Wb = Wall + (size_t)which * Cc * Cc;
    const float* bias = (which == 0) ? bq : (which == 1) ? bk : bv;
    unsigned short* outp = (which == 0) ? qo : (which == 1) ? ko : vo;
    const float scale = (which == 0) ? QSCALE : 1.0f;

    const int tid = threadIdx.x;
    const int lane = tid & 63;
    const int w = tid >> 6;
    const int wr = w >> 1, wc = w & 1;
    const int l15 = lane & 15, lg = lane >> 4;
    const int m0 = blockIdx.x * 128, n0 = blockIdx.y * 128;

    f32x4 acc[4][4] = {};

    for (int k0 = 0; k0 < Cc; k0 += 32) {
        #pragma unroll
        for (int i = 0; i < 2; ++i) {
            const int idx = tid + i * 256;
            const int row = idx >> 2, g = idx & 3;
            *reinterpret_cast<short8*>(&As[row][g * 8]) =
                *reinterpret_cast<const short8*>(&A[(size_t)(m0 + row) * Cc + k0 + g * 8]);
            *reinterpret_cast<short8*>(&Bs[row][g * 8]) =
                *reinterpret_cast<const short8*>(&Wb[(size_t)(n0 + row) * Cc + k0 + g * 8]);
        }
        __syncthreads();
        short8 a[4], b[4];
        #pragma unroll
        for (int mi = 0; mi < 4; ++mi)
            a[mi] = *reinterpret_cast<const short8*>(&As[wr * 64 + mi * 16 + l15][lg * 8]);
        #pragma unroll
        for (int nj = 0; nj < 4; ++nj)
            b[nj] = *reinterpret_cast<const short8*>(&Bs[wc * 64 + nj * 16 + l15][lg * 8]);
        #pragma unroll
        for (int mi = 0; mi < 4; ++mi)
            #pragma unroll
            for (int nj = 0; nj < 4; ++nj)
                acc[mi][nj] = __builtin_amdgcn_mfma_f32_16x16x32_bf16(a[mi], b[nj], acc[mi][nj], 0, 0, 0);
        __syncthreads();
    }

    #pragma unroll
    for (int mi = 0; mi < 4; ++mi) {
        #pragma unroll
        for (int nj = 0; nj < 4; ++nj) {
            const int col = n0 + wc * 64 + nj * 16 + l15;
            const float bvv = bias[col];
            if (which == 2) {
                const int mbase = m0 + wr * 64 + mi * 16 + lg * 4;
                const int b_ = mbase >> 12, t = mbase & (Tt - 1);
                const int h = col >> 6, d = col & 63;
                ushort4v o;
                #pragma unroll
                for (int r = 0; r < 4; ++r)
                    o[r] = f2bf(acc[mi][nj][r] + bvv);
                *reinterpret_cast<ushort4v*>(
                    &outp[(((size_t)b_ * Hh + h) * Dd + d) * Tt + t]) = o;
            } else {
                #pragma unroll
                for (int r = 0; r < 4; ++r) {
                    const int row = m0 + wr * 64 + mi * 16 + lg * 4 + r;
                    const int b_ = row >> 12, t = row & (Tt - 1);
                    const int h = col >> 6, d = col & 63;
                    outp[(((size_t)b_ * Hh + h) * Tt + t) * Dd + d] =
                        f2bf((acc[mi][nj][r] + bvv) * scale);
                }
            }
        }
    }
}

// ---------------------------------------------------------------------------
// Output projection: f32 out, flat [m*C + n]
// ---------------------------------------------------------------------------
__global__ __launch_bounds__(256)
void proj_out(const unsigned short* __restrict__ A, const unsigned short* __restrict__ Wb,
              const float* __restrict__ bias, float* __restrict__ outp) {
    __shared__ unsigned short As[128][32];
    __shared__ unsigned short Bs[128][32];

    const int tid = threadIdx.x;
    const int lane = tid & 63;
    const int w = tid >> 6;
    const int wr = w >> 1, wc = w & 1;
    const int l15 = lane & 15, lg = lane >> 4;
    const int m0 = blockIdx.x * 128, n0 = blockIdx.y * 128;

    f32x4 acc[4][4] = {};

    for (int k0 = 0; k0 < Cc; k0 += 32) {
        #pragma unroll
        for (int i = 0; i < 2; ++i) {
            const int idx = tid + i * 256;
            const int row = idx >> 2, g = idx & 3;
            *reinterpret_cast<short8*>(&As[row][g * 8]) =
                *reinterpret_cast<const short8*>(&A[(size_t)(m0 + row) * Cc + k0 + g * 8]);
            *reinterpret_cast<short8*>(&Bs[row][g * 8]) =
                *reinterpret_cast<const short8*>(&Wb[(size_t)(n0 + row) * Cc + k0 + g * 8]);
        }
        __syncthreads();
        short8 a[4], b[4];
        #pragma unroll
        for (int mi = 0; mi < 4; ++mi)
            a[mi] = *reinterpret_cast<const short8*>(&As[wr * 64 + mi * 16 + l15][lg * 8]);
        #pragma unroll
        for (int nj = 0; nj < 4; ++nj)
            b[nj] = *reinterpret_cast<const short8*>(&Bs[wc * 64 + nj * 16 + l15][lg * 8]);
        #pragma unroll
        for (int mi = 0; mi < 4; ++mi)
            #pragma unroll
            for (int nj = 0; nj < 4; ++nj)
                acc[mi][nj] = __builtin_amdgcn_mfma_f32_16x16x32_bf16(a[mi], b[nj], acc[mi][nj], 0, 0, 0);
        __syncthreads();
    }

    #pragma unroll
    for (int mi = 0; mi < 4; ++mi) {
        #pragma unroll
        for (int nj = 0; nj < 4; ++nj) {
            const int col = n0 + wc * 64 + nj * 16 + l15;
            const float bv = bias[col];
            #pragma unroll
            for (int r = 0; r < 4; ++r) {
                const int row = m0 + wr * 64 + mi * 16 + lg * 4 + r;
                outp[(size_t)row * Cc + col] = acc[mi][nj][r] + bv;
            }
        }
    }
}

// ---------------------------------------------------------------------------
// Causal flash attention, swapped-QK 32x32 MFMA, in-register softmax (exp2).
// Staging: global_load_lds direct into a 3-deep LDS ring, counted vmcnt(4),
// ONE raw s_barrier per tile. Swizzle on SOURCE address (linear LDS dest),
// read side uses the same SW() -> conflict-free frags, no staging VALU.
// Block = 4 waves x 32 q-rows (BQ=128). grid = 512 flat, pair-balanced:
// qt(b) + qt(b+256) = 31 so each CU's two resident blocks sum to ~68 tiles.
// ---------------------------------------------------------------------------
__global__ __launch_bounds__(256)
void attn_mfma(const unsigned short* __restrict__ qb, const unsigned short* __restrict__ kb,
               const unsigned short* __restrict__ vtb, unsigned short* __restrict__ ob) {
    __shared__ unsigned short Ks[3][64][64];    // [ring][kv][d]
    __shared__ unsigned short Vts[3][64][64];   // [ring][d][kv]
    __shared__ float stats[4][32];

    // pair-balanced qt mapping (heavy half dispatched first)
    const int bid = (int)blockIdx.x;
    const int qt = (bid < 256) ? (31 - (bid >> 4)) : ((bid - 256) >> 4);
    const int bh = bid & 15;

    const int tid = threadIdx.x;
    const int w = tid >> 6;
    const int lane = tid & 63;
    const int l31 = lane & 31, hi = lane >> 5;

    const int qg = qt * 128 + w * 32 + l31;

    // Q fragments (B-operand), pre-scaled QSCALE at projection.
    // Loaded FIRST so they are oldest in the vmcnt queue (manual waits subsume).
    short8 qf[4];
    {
        const unsigned short* qp = qb + ((size_t)bh * Tt + qg) * Dd + hi * 8;
        #pragma unroll
        for (int s = 0; s < 4; ++s)
            qf[s] = *reinterpret_cast<const short8*>(qp + s * 16);
    }

    // staging geometry: wave w stages rows [16w,16w+16) of K and of Vt per tile,
    // as 2+2 global_load_lds (8 rows x 128B each). Source granule pre-swizzled.
    const unsigned short* kb_h = kb + (size_t)bh * Tt * Dd;
    const unsigned short* vt_h = vtb + (size_t)bh * Dd * Tt;
    const int r0 = (w << 4) + (lane >> 3);       // rows for sub-instr 0
    const int r1 = r0 + 8;                       // rows for sub-instr 1
    const int gk0 = ((lane & 7) ^ SW(r0)) * 8;   // swizzled granule (elems)
    const int gk1 = ((lane & 7) ^ SW(r1)) * 8;

    f32x16 oacc[2] = {};
    float mrow = -INFINITY, lrow = 0.f;

    const int ntiles = 2 * qt + 2;
    const int qmax_w = qt * 128 + w * 32 + 31;

    // ---- prologue: stage tiles 0,1 into ring 0,1 ----
    #pragma unroll
    for (int t = 0; t < 2; ++t) {
        gload16(kb_h + (size_t)(t * 64 + r0) * Dd + gk0, &Ks[t][(w << 4)][0]);
        gload16(kb_h + (size_t)(t * 64 + r1) * Dd + gk1, &Ks[t][(w << 4) + 8][0]);
        gload16(vt_h + (size_t)r0 * Tt + t * 64 + gk0, &Vts[t][(w << 4)][0]);
        gload16(vt_h + (size_t)r1 * Tt + t * 64 + gk1, &Vts[t][(w << 4) + 8][0]);
    }

    int cur = 0;                                 // ring slot of tile kt
    for (int kt = 0; kt < ntiles; ++kt) {
        // wait: keep stage(kt+1)'s 4 loads in flight, drain stage(kt)
        if (kt + 1 < ntiles) {
            asm volatile("s_waitcnt vmcnt(4)" ::: "memory");
        } else {
            asm volatile("s_waitcnt vmcnt(0)" ::: "memory");
        }
        __builtin_amdgcn_s_barrier();            // buf[cur] ready; buf[stg] free
        __builtin_amdgcn_sched_barrier(0);

        // issue stage(kt+2) into the slot freed by compute(kt-1)
        if (kt + 2 < ntiles) {
            const int stg = (cur + 2 >= 3) ? (cur - 1) : (cur + 2);
            const int n64 = (kt + 2) * 64;
            gload16(kb_h + (size_t)(n64 + r0) * Dd + gk0, &Ks[stg][(w << 4)][0]);
            gload16(kb_h + (size_t)(n64 + r1) * Dd + gk1, &Ks[stg][(w << 4) + 8][0]);
            gload16(vt_h + (size_t)r0 * Tt + n64 + gk0, &Vts[stg][(w << 4)][0]);
            gload16(vt_h + (size_t)r1 * Tt + n64 + gk1, &Vts[stg][(w << 4) + 8][0]);
        }

        if (kt * 64 <= qmax_w) {
            // ---- S^T = K Q^T : sacc[f][reg]=S[kv][q], kv=(r&3)+8*(r>>2)+4*hi+32f
            f32x16 sacc[2];
            #pragma unroll
            for (int f = 0; f < 2; ++f) {
                f32x16 z = {};
                const int krow = f * 32 + l31;
                const int sw = SW(krow);
                #pragma unroll
                for (int s = 0; s < 4; ++s) {
                    const short8 kf = *reinterpret_cast<const short8*>(
                        &Ks[cur][krow][((2 * s + hi) ^ sw) * 8]);
                    z = __builtin_amdgcn_mfma_f32_32x32x16_bf16(kf, qf[s], z, 0, 0, 0);
                }
                sacc[f] = z;
            }

            // ---- causal mask ----
            if (kt * 64 + 63 > qt * 128 + w * 32) {
                #pragma unroll
                for (int f = 0; f < 2; ++f)
                    #pragma unroll
                    for (int r = 0; r < 16; ++r) {
                        const int kvg = kt * 64 + f * 32 + (r & 3) + 8 * (r >> 2) + 4 * hi;
                        if (kvg > qg) sacc[f][r] = -INFINITY;
                    }
            }

            // ---- row max ----
            float pmax = sacc[0][0];
            #pragma unroll
            for (int r = 1; r < 16; ++r) pmax = fmaxf(pmax, sacc[0][r]);
            #pragma unroll
            for (int r = 0; r < 16; ++r) pmax = fmaxf(pmax, sacc[1][r]);
            pmax = fmaxf(pmax, __shfl_xor(pmax, 32));

            // ---- defer-max rescale ----
            if (__any(pmax > mrow + DEFER_THR)) {
                const float mnew = fmaxf(mrow, pmax);
                const float corr = exp2f(mrow - mnew);
                mrow = mnew;
                lrow *= corr;
                stats[w][l31] = corr;
                #pragma unroll
                for (int r = 0; r < 16; ++r) {
                    const float c = stats[w][(r & 3) + 8 * (r >> 2) + 4 * hi];
                    oacc[0][r] *= c;
                    oacc[1][r] *= c;
                }
            }

            // ---- P = exp2(S - m), row sum ----
            float rs = 0.f;
            #pragma unroll
            for (int f = 0; f < 2; ++f)
                #pragma unroll
                for (int r = 0; r < 16; ++r) {
                    const float p = exp2f(sacc[f][r] - mrow);
                    sacc[f][r] = p;
                    rs += p;
                }
            lrow += rs;

            // ---- P -> bf16 A-frags (cvt_pk + permlane32_swap); O += P V ----
            #pragma unroll
            for (int f = 0; f < 2; ++f) {
                #pragma unroll
                for (int s2 = 0; s2 < 2; ++s2) {
                    const int b0 = s2 * 8;
                    unsigned int c01 = cvtpk_bf16(sacc[f][b0 + 0], sacc[f][b0 + 1]);
                    unsigned int c23 = cvtpk_bf16(sacc[f][b0 + 2], sacc[f][b0 + 3]);
                    unsigned int c45 = cvtpk_bf16(sacc[f][b0 + 4], sacc[f][b0 + 5]);
                    unsigned int c67 = cvtpk_bf16(sacc[f][b0 + 6], sacc[f][b0 + 7]);
                    asm("v_permlane32_swap_b32 %0, %1" : "+v"(c01), "+v"(c45));
                    asm("v_permlane32_swap_b32 %0, %1" : "+v"(c23), "+v"(c67));
                    uint4v paw;
                    paw[0] = c01; paw[1] = c23; paw[2] = c45; paw[3] = c67;
                    const short8 pa = *reinterpret_cast<short8*>(&paw);
                    const int g = 4 * f + 2 * s2;
                    #pragma unroll
                    for (int nb = 0; nb < 2; ++nb) {
                        const int vrow = nb * 32 + l31;
                        const short8 vf = *reinterpret_cast<const short8*>(
                            &Vts[cur][vrow][((g + hi) ^ SW(vrow)) * 8]);
                        oacc[nb] = __builtin_amdgcn_mfma_f32_32x32x16_bf16(pa, vf, oacc[nb], 0, 0, 0);
                    }
                }
            }
        }

        cur = (cur == 2) ? 0 : cur + 1;
    }

    // ---- epilogue: 1/l broadcast (wave-private slab), normalize, bf16 out ----
    const float lf = lrow + __shfl_xor(lrow, 32);
    stats[w][l31] = 1.f / lf;
    const int b_ = bh >> 3, h = bh & 7;
    #pragma unroll
    for (int r = 0; r < 16; ++r) {
        const int qr = (r & 3) + 8 * (r >> 2) + 4 * hi;
        const float linv = stats[w][qr];
        const int tg = qt * 128 + w * 32 + qr;
        unsigned short* dst = ob + ((size_t)b_ * Tt + tg) * Cc + h * Dd + l31;
        dst[0]  = f2bf(oacc[0][r] * linv);
        dst[32] = f2bf(oacc[1][r] * linv);
    }
}

// ---------------------------------------------------------------------------
extern "C" void kernel_launch(void* const* d_in, const int* in_sizes, int n_in,
                              void* d_out, int out_size, void* d_ws, size_t ws_size,
                              hipStream_t stream) {
    const float* x  = (const float*)d_in[0];
    const float* wq = (const float*)d_in[1];
    const float* bq = (const float*)d_in[2];
    const float* wk = (const float*)d_in[3];
    const float* bk = (const float*)d_in[4];
    const float* wv = (const float*)d_in[5];
    const float* bv = (const float*)d_in[6];
    const float* wo = (const float*)d_in[7];
    const float* bo = (const float*)d_in[8];
    float* out = (float*)d_out;

    const size_t nTok = (size_t)Mtot * Cc;
    const size_t nW   = (size_t)Cc * Cc;

    unsigned short* xb    = (unsigned short*)d_ws;
    unsigned short* wqb   = xb + nTok;           // wq,wk,wv,wo consecutive
    unsigned short* wob   = wqb + 3 * nW;
    unsigned short* qbuf  = wqb + 4 * nW;        // [B,H,T,D] bf16 (pre-scaled)
    unsigned short* kbuf  = qbuf + nTok;         // [B,H,T,D] bf16
    unsigned short* vtbuf = kbuf + nTok;         // [B,H,D,T] bf16
    unsigned short* oattb = vtbuf + nTok;        // [B,T,C]  bf16

    cast_f32_bf16<<<dim3((unsigned)(nTok / 8 / 256)), 256, 0, stream>>>(x, xb);
    cast_w4<<<dim3((unsigned)(nW / 8 / 256), 4), 256, 0, stream>>>(wq, wk, wv, wo, wqb);

    proj_qkv<<<dim3(Mtot / 128, Cc / 128, 3), 256, 0, stream>>>(
        xb, wqb, bq, bk, bv, qbuf, kbuf, vtbuf);

    attn_mfma<<<dim3(512), 256, 0, stream>>>(qbuf, kbuf, vtbuf, oattb);

    proj_out<<<dim3(Mtot / 128, Cc / 128), 256, 0, stream>>>(oattb, wob, bo, out);
}